// Round 1
// baseline (2913.876 us; speedup 1.0000x reference)
//
#include <hip/hip_runtime.h>
#include <hip/hip_bf16.h>

#define NN 8192
#define EE 262144
#define DD 256
#define FF 512
#define MM 256

// ---------------- CSR build ----------------
__global__ void init_kernel(int* degi, int* cursor) {
  int i = blockIdx.x * blockDim.x + threadIdx.x;
  if (i < NN) { degi[i] = 0; cursor[i] = 0; }
}

__global__ void count_kernel(const int* __restrict__ ei, int* __restrict__ degi) {
  int i = blockIdx.x * blockDim.x + threadIdx.x;
  if (i < EE) atomicAdd(&degi[ei[EE + i]], 1);
}

__global__ __launch_bounds__(1024) void scan_kernel(const int* __restrict__ degi,
                                                    int* __restrict__ csr_off) {
  __shared__ int part[1024];
  int tid = threadIdx.x;
  int base = tid * 8;
  int loc[8]; int s = 0;
#pragma unroll
  for (int i = 0; i < 8; ++i) { loc[i] = s; s += degi[base + i]; }
  part[tid] = s;
  __syncthreads();
  for (int off = 1; off < 1024; off <<= 1) {
    int v = (tid >= off) ? part[tid - off] : 0;
    __syncthreads();
    part[tid] += v;
    __syncthreads();
  }
  int pre = (tid == 0) ? 0 : part[tid - 1];
#pragma unroll
  for (int i = 0; i < 8; ++i) csr_off[base + i] = pre + loc[i];
  if (tid == 1023) csr_off[NN] = part[1023];
}

__global__ void dinv_kernel(const int* __restrict__ degi, float* __restrict__ dinv) {
  int i = blockIdx.x * blockDim.x + threadIdx.x;
  if (i < NN) dinv[i] = rsqrtf((float)(degi[i] + 1));  // +1 = self loop
}

__global__ void fill_kernel(const int* __restrict__ ei, const int* __restrict__ csr_off,
                            int* __restrict__ cursor, int* __restrict__ csr_src) {
  int i = blockIdx.x * blockDim.x + threadIdx.x;
  if (i < EE) {
    int d = ei[EE + i];
    int pos = csr_off[d] + atomicAdd(&cursor[d], 1);
    csr_src[pos] = ei[i];
  }
}

// ---------------- small precompute ----------------
__global__ void transpose_kernel(const float* __restrict__ RF, float* __restrict__ RFT) {
  int i = blockIdx.x * blockDim.x + threadIdx.x;  // 65536
  int m = i >> 8, d = i & 255;
  RFT[d * MM + m] = RF[i];
}

__global__ void rf_bias_kernel(const float* __restrict__ bvec, const float* __restrict__ RF,
                               float* __restrict__ outb, float alpha) {
  int m = threadIdx.x;
  float s = 0.0f;
  for (int j = 0; j < DD; ++j) s = fmaf(bvec[j], RF[m * DD + j], s);
  outb[m] = s * alpha;
}

// ---------------- generic fp32 GEMM: C = alpha*(A@B) + bias, optional relu ----------------
template<bool RELU>
__global__ __launch_bounds__(256) void gemm_kernel(
    const float* __restrict__ A, const float* __restrict__ B,
    const float* __restrict__ bias, float* __restrict__ C,
    int n, int K, int Dout, float alpha)
{
  __shared__ float As[16][68];
  __shared__ float Bs[16][68];
  const int tid = threadIdx.x;
  const int tx = tid & 15, ty = tid >> 4;
  const int n0 = blockIdx.x * 64;
  const int m0 = blockIdx.y * 64;
  float acc[4][4] = {};
  for (int k0 = 0; k0 < K; k0 += 16) {
    {
      int m = tid & 63, kq = (tid >> 6) << 2;
      float4 a4 = *reinterpret_cast<const float4*>(&A[(m0 + m) * K + k0 + kq]);
      As[kq + 0][m] = a4.x; As[kq + 1][m] = a4.y; As[kq + 2][m] = a4.z; As[kq + 3][m] = a4.w;
      int kk = tid >> 4, nn4 = (tid & 15) << 2;
      *reinterpret_cast<float4*>(&Bs[kk][nn4]) =
          *reinterpret_cast<const float4*>(&B[(k0 + kk) * Dout + n0 + nn4]);
    }
    __syncthreads();
#pragma unroll
    for (int kk = 0; kk < 16; ++kk) {
      float4 av = *reinterpret_cast<const float4*>(&As[kk][ty << 2]);
      float4 bv = *reinterpret_cast<const float4*>(&Bs[kk][tx << 2]);
      float a[4] = {av.x, av.y, av.z, av.w};
      float b[4] = {bv.x, bv.y, bv.z, bv.w};
#pragma unroll
      for (int i = 0; i < 4; ++i)
#pragma unroll
        for (int j = 0; j < 4; ++j)
          acc[i][j] = fmaf(a[i], b[j], acc[i][j]);
    }
    __syncthreads();
  }
#pragma unroll
  for (int i = 0; i < 4; ++i) {
    int row = m0 + (ty << 2) + i;
    int col = n0 + (tx << 2);
    float4 o;
    float* po = &o.x;
#pragma unroll
    for (int j = 0; j < 4; ++j) {
      float c = acc[i][j] * alpha + (bias ? bias[col + j] : 0.0f);
      if (RELU) c = fmaxf(c, 0.0f);
      po[j] = c;
    }
    *reinterpret_cast<float4*>(&C[row * Dout + col]) = o;
  }
}

// ---------------- GCN gather + residual + LN1 ----------------
__global__ __launch_bounds__(256) void gcn_gather_ln_kernel(
    const float* __restrict__ xw, const float* __restrict__ h,
    const float* __restrict__ dinv, const int* __restrict__ csr_off,
    const int* __restrict__ csr_src, const float* __restrict__ b_gcn,
    const float* __restrict__ g1, const float* __restrict__ be1,
    float* __restrict__ h1)
{
  __shared__ float2 red[256];
  const int node = blockIdx.x;
  const int c = threadIdx.x;
  const float di = dinv[node];
  const int e0 = csr_off[node], e1 = csr_off[node + 1];
  float acc = 0.0f;
  for (int e = e0; e < e1; ++e) {
    int s = csr_src[e];
    acc = fmaf(xw[s * DD + c], dinv[s], acc);
  }
  float y = fmaf(acc, di, xw[node * DD + c] * di * di);  // edges*di + self*di^2
  y += b_gcn[c];
  y += h[node * DD + c];
  red[c] = make_float2(y, y * y);
  __syncthreads();
  for (int sft = 128; sft > 0; sft >>= 1) {
    if (c < sft) { red[c].x += red[c + sft].x; red[c].y += red[c + sft].y; }
    __syncthreads();
  }
  float mu = red[0].x * (1.0f / 256.0f);
  float var = red[0].y * (1.0f / 256.0f) - mu * mu;
  float inv = rsqrtf(fmaxf(var, 0.0f) + 1e-5f);
  h1[node * DD + c] = (y - mu) * inv * g1[c] + be1[c];
}

// ---------------- residual + LN ----------------
__global__ __launch_bounds__(256) void ln_res_kernel(
    const float* __restrict__ a, const float* __restrict__ b,
    const float* __restrict__ g, const float* __restrict__ be,
    float* __restrict__ out)
{
  __shared__ float2 red[256];
  const int row = blockIdx.x;
  const int c = threadIdx.x;
  float y = a[row * DD + c] + b[row * DD + c];
  red[c] = make_float2(y, y * y);
  __syncthreads();
  for (int sft = 128; sft > 0; sft >>= 1) {
    if (c < sft) { red[c].x += red[c + sft].x; red[c].y += red[c + sft].y; }
    __syncthreads();
  }
  float mu = red[0].x * (1.0f / 256.0f);
  float var = red[0].y * (1.0f / 256.0f) - mu * mu;
  float inv = rsqrtf(fmaxf(var, 0.0f) + 1e-5f);
  out[row * DD + c] = (y - mu) * inv * g[c] + be[c];
}

// ---------------- flash attention (fp32), qf pre-scaled by 1/16 ----------------
#define FA_LD 260
__global__ __launch_bounds__(256) void flash_kernel(
    const float* __restrict__ qf, const float* __restrict__ kf,
    const float* __restrict__ vv, float* __restrict__ hg)
{
  __shared__ float Qs[32][FA_LD];
  __shared__ float Ks[32][FA_LD];
  __shared__ float Vs[32][FA_LD];
  __shared__ float Ss[32][33];
  __shared__ float m_s[32], l_s[32], sc_s[32];

  const int tid = threadIdx.x;
  const int q0 = blockIdx.x * 32;
  for (int i = tid * 4; i < 32 * 256; i += 1024) {
    float4 t4 = *reinterpret_cast<const float4*>(&qf[q0 * 256 + i]);
    *reinterpret_cast<float4*>(&Qs[i >> 8][i & 255]) = t4;
  }
  if (tid < 32) { m_s[tid] = -1e30f; l_s[tid] = 0.0f; }
  float acc[4][8] = {};
  const int j  = tid & 31;
  const int rb = tid >> 5;  // 0..7
  const int ty = tid >> 5;
  const int tx = tid & 31;

  for (int k0 = 0; k0 < NN; k0 += 32) {
    __syncthreads();  // protect Ks/Vs (and first-iter Q/m/l init)
    for (int i = tid * 4; i < 32 * 256; i += 1024) {
      *reinterpret_cast<float4*>(&Ks[i >> 8][i & 255]) =
          *reinterpret_cast<const float4*>(&kf[k0 * 256 + i]);
      *reinterpret_cast<float4*>(&Vs[i >> 8][i & 255]) =
          *reinterpret_cast<const float4*>(&vv[k0 * 256 + i]);
    }
    __syncthreads();
    // S = Qs @ Ks^T : each thread does 4 rows (rb, rb+8, rb+16, rb+24) x 1 col j
    float a0 = 0.f, a1 = 0.f, a2 = 0.f, a3 = 0.f;
#pragma unroll 4
    for (int kk = 0; kk < 256; kk += 4) {
      float4 kv  = *reinterpret_cast<const float4*>(&Ks[j][kk]);
      float4 q0v = *reinterpret_cast<const float4*>(&Qs[rb][kk]);
      float4 q1v = *reinterpret_cast<const float4*>(&Qs[rb + 8][kk]);
      float4 q2v = *reinterpret_cast<const float4*>(&Qs[rb + 16][kk]);
      float4 q3v = *reinterpret_cast<const float4*>(&Qs[rb + 24][kk]);
      a0 = fmaf(q0v.x, kv.x, a0); a0 = fmaf(q0v.y, kv.y, a0);
      a0 = fmaf(q0v.z, kv.z, a0); a0 = fmaf(q0v.w, kv.w, a0);
      a1 = fmaf(q1v.x, kv.x, a1); a1 = fmaf(q1v.y, kv.y, a1);
      a1 = fmaf(q1v.z, kv.z, a1); a1 = fmaf(q1v.w, kv.w, a1);
      a2 = fmaf(q2v.x, kv.x, a2); a2 = fmaf(q2v.y, kv.y, a2);
      a2 = fmaf(q2v.z, kv.z, a2); a2 = fmaf(q2v.w, kv.w, a2);
      a3 = fmaf(q3v.x, kv.x, a3); a3 = fmaf(q3v.y, kv.y, a3);
      a3 = fmaf(q3v.z, kv.z, a3); a3 = fmaf(q3v.w, kv.w, a3);
    }
    Ss[rb][j] = a0; Ss[rb + 8][j] = a1; Ss[rb + 16][j] = a2; Ss[rb + 24][j] = a3;
    __syncthreads();
    if (tid < 32) {
      int r = tid;
      float mo = m_s[r];
      float mx = mo;
#pragma unroll
      for (int jj = 0; jj < 32; ++jj) mx = fmaxf(mx, Ss[r][jj]);
      float scale = __expf(mo - mx);
      float sum = 0.0f;
#pragma unroll
      for (int jj = 0; jj < 32; ++jj) {
        float p = __expf(Ss[r][jj] - mx);
        Ss[r][jj] = p;
        sum += p;
      }
      l_s[r] = l_s[r] * scale + sum;
      m_s[r] = mx;
      sc_s[r] = scale;
    }
    __syncthreads();
#pragma unroll
    for (int rr = 0; rr < 4; ++rr) {
      float s = sc_s[ty * 4 + rr];
#pragma unroll
      for (int cc = 0; cc < 8; ++cc) acc[rr][cc] *= s;
    }
    for (int jj = 0; jj < 32; ++jj) {
      float p0 = Ss[ty * 4 + 0][jj];
      float p1 = Ss[ty * 4 + 1][jj];
      float p2 = Ss[ty * 4 + 2][jj];
      float p3 = Ss[ty * 4 + 3][jj];
#pragma unroll
      for (int cc = 0; cc < 8; ++cc) {
        float vvv = Vs[jj][tx + (cc << 5)];
        acc[0][cc] = fmaf(p0, vvv, acc[0][cc]);
        acc[1][cc] = fmaf(p1, vvv, acc[1][cc]);
        acc[2][cc] = fmaf(p2, vvv, acc[2][cc]);
        acc[3][cc] = fmaf(p3, vvv, acc[3][cc]);
      }
    }
  }
#pragma unroll
  for (int rr = 0; rr < 4; ++rr) {
    float inv = 1.0f / l_s[ty * 4 + rr];
    int row = q0 + ty * 4 + rr;
#pragma unroll
    for (int cc = 0; cc < 8; ++cc)
      hg[row * 256 + tx + (cc << 5)] = acc[rr][cc] * inv;
  }
}

extern "C" void kernel_launch(void* const* d_in, const int* in_sizes, int n_in,
                              void* d_out, int out_size, void* d_ws, size_t ws_size,
                              hipStream_t stream) {
  (void)in_sizes; (void)n_in; (void)out_size; (void)ws_size;
  const float* h     = (const float*)d_in[0];
  const int*   ei    = (const int*)  d_in[1];
  const float* W_gcn = (const float*)d_in[2];
  const float* b_gcn = (const float*)d_in[3];
  const float* Wq    = (const float*)d_in[4];
  const float* bq    = (const float*)d_in[5];
  const float* Wk    = (const float*)d_in[6];
  const float* bk    = (const float*)d_in[7];
  const float* Wv    = (const float*)d_in[8];
  const float* bv    = (const float*)d_in[9];
  const float* Wo    = (const float*)d_in[10];
  const float* bo    = (const float*)d_in[11];
  const float* RF    = (const float*)d_in[12];
  const float* g1    = (const float*)d_in[13];
  const float* be1   = (const float*)d_in[14];
  const float* g2    = (const float*)d_in[15];
  const float* be2   = (const float*)d_in[16];
  const float* g3    = (const float*)d_in[17];
  const float* be3   = (const float*)d_in[18];
  const float* W1    = (const float*)d_in[19];
  const float* b1    = (const float*)d_in[20];
  const float* W2    = (const float*)d_in[21];
  const float* b2    = (const float*)d_in[22];
  float* out = (float*)d_out;

  float* w = (float*)d_ws;
  float* xw  = w; w += NN * DD;   // later reused as hgo
  float* h1  = w; w += NN * DD;
  float* qf  = w; w += NN * MM;   // later reused (with kf) as ffn hidden t
  float* kf  = w; w += NN * MM;
  float* vv  = w; w += NN * DD;   // later reused as f2
  float* hg  = w; w += NN * DD;   // later reused as h2
  float* RFT = w; w += DD * MM;
  float* WqRF= w; w += DD * MM;
  float* WkRF= w; w += DD * MM;
  float* bqRF= w; w += MM;
  float* bkRF= w; w += MM;
  float* dinv= w; w += NN;
  int* ib = (int*)w;
  int* degi    = ib; ib += NN;
  int* cursor  = ib; ib += NN;
  int* csr_off = ib; ib += NN + 4;
  int* csr_src = ib; ib += EE;

  float* t  = qf;  // 8192x512 ffn hidden (spans qf+kf)
  float* f2 = vv;
  float* h2 = hg;
  float* hgo = xw;

  // CSR build
  init_kernel<<<NN / 256, 256, 0, stream>>>(degi, cursor);
  count_kernel<<<EE / 256, 256, 0, stream>>>(ei, degi);
  scan_kernel<<<1, 1024, 0, stream>>>(degi, csr_off);
  dinv_kernel<<<NN / 256, 256, 0, stream>>>(degi, dinv);
  fill_kernel<<<EE / 256, 256, 0, stream>>>(ei, csr_off, cursor, csr_src);
  // xw = h @ W_gcn
  gemm_kernel<false><<<dim3(DD / 64, NN / 64), 256, 0, stream>>>(h, W_gcn, nullptr, xw, NN, DD, DD, 1.0f);
  // folded RF projections: Wq' = (Wq @ RF^T)/16, Wk' = Wk @ RF^T
  transpose_kernel<<<DD * MM / 256, 256, 0, stream>>>(RF, RFT);
  gemm_kernel<false><<<dim3(MM / 64, DD / 64), 256, 0, stream>>>(Wq, RFT, nullptr, WqRF, DD, DD, MM, 1.0f / 16.0f);
  gemm_kernel<false><<<dim3(MM / 64, DD / 64), 256, 0, stream>>>(Wk, RFT, nullptr, WkRF, DD, DD, MM, 1.0f);
  rf_bias_kernel<<<1, MM, 0, stream>>>(bq, RF, bqRF, 1.0f / 16.0f);
  rf_bias_kernel<<<1, MM, 0, stream>>>(bk, RF, bkRF, 1.0f);
  // local GCN + LN1
  gcn_gather_ln_kernel<<<NN, 256, 0, stream>>>(xw, h, dinv, csr_off, csr_src, b_gcn, g1, be1, h1);
  // projections
  gemm_kernel<false><<<dim3(MM / 64, NN / 64), 256, 0, stream>>>(h1, WqRF, bqRF, qf, NN, DD, MM, 1.0f);
  gemm_kernel<false><<<dim3(MM / 64, NN / 64), 256, 0, stream>>>(h1, WkRF, bkRF, kf, NN, DD, MM, 1.0f);
  gemm_kernel<false><<<dim3(DD / 64, NN / 64), 256, 0, stream>>>(h1, Wv, bv, vv, NN, DD, DD, 1.0f);
  // attention (online softmax)
  flash_kernel<<<NN / 32, 256, 0, stream>>>(qf, kf, vv, hg);
  // output projection + LN2
  gemm_kernel<false><<<dim3(DD / 64, NN / 64), 256, 0, stream>>>(hg, Wo, bo, hgo, NN, DD, DD, 1.0f);
  ln_res_kernel<<<NN, 256, 0, stream>>>(h1, hgo, g2, be2, h2);
  // FFN + LN3
  gemm_kernel<true ><<<dim3(FF / 64, NN / 64), 256, 0, stream>>>(h2, W1, b1, t, NN, DD, FF, 1.0f);
  gemm_kernel<false><<<dim3(DD / 64, NN / 64), 256, 0, stream>>>(t, W2, b2, f2, NN, FF, DD, 1.0f);
  ln_res_kernel<<<NN, 256, 0, stream>>>(h2, f2, g3, be3, out);
}

// Round 2
// 571.142 us; speedup vs baseline: 5.1018x; 5.1018x over previous
//
#include <hip/hip_runtime.h>
#include <hip/hip_bf16.h>

#define NN 8192
#define EE 262144
#define DD 256
#define FF 512
#define MM 256
#define KSPLIT 4
#define KCHUNK (NN / KSPLIT)

typedef __attribute__((ext_vector_type(8))) short short8v;
typedef __attribute__((ext_vector_type(4))) float float4v;

__device__ __forceinline__ ushort f2bf(float x) {
  union { float f; unsigned u; } c; c.f = x;
  unsigned r = (c.u + 0x7FFF + ((c.u >> 16) & 1)) >> 16;
  return (ushort)r;
}

// ---------------- CSR build ----------------
__global__ void init_kernel(int* degi, int* cursor) {
  int i = blockIdx.x * blockDim.x + threadIdx.x;
  if (i < NN) { degi[i] = 0; cursor[i] = 0; }
}

__global__ void count_kernel(const int* __restrict__ ei, int* __restrict__ degi) {
  int i = blockIdx.x * blockDim.x + threadIdx.x;
  if (i < EE) atomicAdd(&degi[ei[EE + i]], 1);
}

__global__ __launch_bounds__(1024) void scan_kernel(const int* __restrict__ degi,
                                                    int* __restrict__ csr_off) {
  __shared__ int part[1024];
  int tid = threadIdx.x;
  int base = tid * 8;
  int loc[8]; int s = 0;
#pragma unroll
  for (int i = 0; i < 8; ++i) { loc[i] = s; s += degi[base + i]; }
  part[tid] = s;
  __syncthreads();
  for (int off = 1; off < 1024; off <<= 1) {
    int v = (tid >= off) ? part[tid - off] : 0;
    __syncthreads();
    part[tid] += v;
    __syncthreads();
  }
  int pre = (tid == 0) ? 0 : part[tid - 1];
#pragma unroll
  for (int i = 0; i < 8; ++i) csr_off[base + i] = pre + loc[i];
  if (tid == 1023) csr_off[NN] = part[1023];
}

__global__ void dinv_kernel(const int* __restrict__ degi, float* __restrict__ dinv) {
  int i = blockIdx.x * blockDim.x + threadIdx.x;
  if (i < NN) dinv[i] = rsqrtf((float)(degi[i] + 1));  // +1 = self loop
}

__global__ void fill_kernel(const int* __restrict__ ei, const int* __restrict__ csr_off,
                            int* __restrict__ cursor, int* __restrict__ csr_src) {
  int i = blockIdx.x * blockDim.x + threadIdx.x;
  if (i < EE) {
    int d = ei[EE + i];
    int pos = csr_off[d] + atomicAdd(&cursor[d], 1);
    csr_src[pos] = ei[i];
  }
}

// ---------------- small precompute ----------------
__global__ void transpose_kernel(const float* __restrict__ RF, float* __restrict__ RFT) {
  int i = blockIdx.x * blockDim.x + threadIdx.x;  // 65536
  int m = i >> 8, d = i & 255;
  RFT[d * MM + m] = RF[i];
}

__global__ void rf_bias_kernel(const float* __restrict__ bvec, const float* __restrict__ RF,
                               float* __restrict__ outb, float alpha) {
  int m = threadIdx.x;
  float s = 0.0f;
  for (int j = 0; j < DD; ++j) s = fmaf(bvec[j], RF[m * DD + j], s);
  outb[m] = s * alpha;
}

// ---------------- generic fp32 GEMM: C = alpha*(A@B) + bias, optional relu, optional bf16 out ----------------
template<bool RELU, bool BF16OUT>
__global__ __launch_bounds__(256) void gemm_kernel(
    const float* __restrict__ A, const float* __restrict__ B,
    const float* __restrict__ bias, void* __restrict__ Cv,
    int n, int K, int Dout, float alpha)
{
  __shared__ float As[16][68];
  __shared__ float Bs[16][68];
  const int tid = threadIdx.x;
  const int tx = tid & 15, ty = tid >> 4;
  const int n0 = blockIdx.x * 64;
  const int m0 = blockIdx.y * 64;
  float acc[4][4] = {};
  for (int k0 = 0; k0 < K; k0 += 16) {
    {
      int m = tid & 63, kq = (tid >> 6) << 2;
      float4 a4 = *reinterpret_cast<const float4*>(&A[(m0 + m) * K + k0 + kq]);
      As[kq + 0][m] = a4.x; As[kq + 1][m] = a4.y; As[kq + 2][m] = a4.z; As[kq + 3][m] = a4.w;
      int kk = tid >> 4, nn4 = (tid & 15) << 2;
      *reinterpret_cast<float4*>(&Bs[kk][nn4]) =
          *reinterpret_cast<const float4*>(&B[(k0 + kk) * Dout + n0 + nn4]);
    }
    __syncthreads();
#pragma unroll
    for (int kk = 0; kk < 16; ++kk) {
      float4 av = *reinterpret_cast<const float4*>(&As[kk][ty << 2]);
      float4 bv = *reinterpret_cast<const float4*>(&Bs[kk][tx << 2]);
      float a[4] = {av.x, av.y, av.z, av.w};
      float b[4] = {bv.x, bv.y, bv.z, bv.w};
#pragma unroll
      for (int i = 0; i < 4; ++i)
#pragma unroll
        for (int j = 0; j < 4; ++j)
          acc[i][j] = fmaf(a[i], b[j], acc[i][j]);
    }
    __syncthreads();
  }
#pragma unroll
  for (int i = 0; i < 4; ++i) {
    int row = m0 + (ty << 2) + i;
    int col = n0 + (tx << 2);
    float vals[4];
#pragma unroll
    for (int j = 0; j < 4; ++j) {
      float c = acc[i][j] * alpha + (bias ? bias[col + j] : 0.0f);
      if (RELU) c = fmaxf(c, 0.0f);
      vals[j] = c;
    }
    if (BF16OUT) {
      ushort* C = (ushort*)Cv;
#pragma unroll
      for (int j = 0; j < 4; ++j) C[(size_t)row * Dout + col + j] = f2bf(vals[j]);
    } else {
      float* C = (float*)Cv;
      float4 o = make_float4(vals[0], vals[1], vals[2], vals[3]);
      *reinterpret_cast<float4*>(&C[(size_t)row * Dout + col]) = o;
    }
  }
}

// ---------------- GCN gather + residual + LN1 ----------------
__global__ __launch_bounds__(256) void gcn_gather_ln_kernel(
    const float* __restrict__ xw, const float* __restrict__ h,
    const float* __restrict__ dinv, const int* __restrict__ csr_off,
    const int* __restrict__ csr_src, const float* __restrict__ b_gcn,
    const float* __restrict__ g1, const float* __restrict__ be1,
    float* __restrict__ h1)
{
  __shared__ float2 red[256];
  const int node = blockIdx.x;
  const int c = threadIdx.x;
  const float di = dinv[node];
  const int e0 = csr_off[node], e1 = csr_off[node + 1];
  float acc = 0.0f;
  for (int e = e0; e < e1; ++e) {
    int s = csr_src[e];
    acc = fmaf(xw[s * DD + c], dinv[s], acc);
  }
  float y = fmaf(acc, di, xw[node * DD + c] * di * di);
  y += b_gcn[c];
  y += h[node * DD + c];
  red[c] = make_float2(y, y * y);
  __syncthreads();
  for (int sft = 128; sft > 0; sft >>= 1) {
    if (c < sft) { red[c].x += red[c + sft].x; red[c].y += red[c + sft].y; }
    __syncthreads();
  }
  float mu = red[0].x * (1.0f / 256.0f);
  float var = red[0].y * (1.0f / 256.0f) - mu * mu;
  float inv = rsqrtf(fmaxf(var, 0.0f) + 1e-5f);
  h1[node * DD + c] = (y - mu) * inv * g1[c] + be1[c];
}

// ---------------- residual + LN ----------------
__global__ __launch_bounds__(256) void ln_res_kernel(
    const float* __restrict__ a, const float* __restrict__ b,
    const float* __restrict__ g, const float* __restrict__ be,
    float* __restrict__ out)
{
  __shared__ float2 red[256];
  const int row = blockIdx.x;
  const int c = threadIdx.x;
  float y = a[row * DD + c] + b[row * DD + c];
  red[c] = make_float2(y, y * y);
  __syncthreads();
  for (int sft = 128; sft > 0; sft >>= 1) {
    if (c < sft) { red[c].x += red[c + sft].x; red[c].y += red[c + sft].y; }
    __syncthreads();
  }
  float mu = red[0].x * (1.0f / 256.0f);
  float var = red[0].y * (1.0f / 256.0f) - mu * mu;
  float inv = rsqrtf(fmaxf(var, 0.0f) + 1e-5f);
  out[row * DD + c] = (y - mu) * inv * g[c] + be[c];
}

// ---------------- MFMA flash attention ----------------
// 128 q-rows/block, 4 waves x 32 rows (2 row-tiles of 16), BK=32 keys/iter.
// Q in registers (bf16 A-frags). K in LDS, XOR-swizzled. V in LDS transposed [d][key].
// Online softmax in registers on C-frag layout (row=(l>>4)*4+r, col=l&15).
// P round-trips through per-wave LDS to reach A-frag layout. KSPLIT partials merged later.
__global__ __launch_bounds__(256, 1) void flash_mfma_kernel(
    const ushort* __restrict__ qb, const ushort* __restrict__ kb,
    const ushort* __restrict__ vb,
    float* __restrict__ op0, float* __restrict__ op1,
    float* __restrict__ op2, float* __restrict__ op3,
    float2* __restrict__ ml)
{
  __shared__ ushort Ksm[32 * 256];      // swizzled row-major [key][m]
  __shared__ ushort Vts[256 * 40];      // transposed [d][key], rows padded to 40
  __shared__ ushort Ps[4][32 * 40];     // per-wave P tile [row][key], padded

  const int tid = threadIdx.x;
  const int l  = tid & 63;
  const int wv = tid >> 6;
  const int lr = l & 15;   // row-in-tile (A/C) / col (B)
  const int lg = l >> 4;   // lane group 0..3
  const int qt = blockIdx.x / KSPLIT;
  const int ks = blockIdx.x % KSPLIT;
  const int q0 = qt * 128;

  // Q fragments (32 rows x 256 feat per wave)
  short8v qfr[2][8];
#pragma unroll
  for (int rt = 0; rt < 2; ++rt)
#pragma unroll
    for (int kk = 0; kk < 8; ++kk)
      qfr[rt][kk] = *(const short8v*)(qb + (size_t)(q0 + wv * 32 + rt * 16 + lr) * MM + kk * 32 + lg * 8);

  float4v acc[2][16];
#pragma unroll
  for (int rt = 0; rt < 2; ++rt)
#pragma unroll
    for (int dt = 0; dt < 16; ++dt)
      acc[rt][dt] = (float4v){0.f, 0.f, 0.f, 0.f};
  float mreg[2][4], lreg[2][4];
#pragma unroll
  for (int rt = 0; rt < 2; ++rt)
#pragma unroll
    for (int r = 0; r < 4; ++r) { mreg[rt][r] = -1e30f; lreg[rt][r] = 0.f; }

  const int krow = tid >> 3, kseg = tid & 7;  // K staging: 32 rows x 8 segs of 64B
  const int vkey = tid & 31, vdg = tid >> 5;  // V staging: 32 keys x 8 d-groups of 32

  for (int it = 0; it < KCHUNK / 32; ++it) {
    const int kg = ks * KCHUNK + it * 32;
    __syncthreads();
    // ---- stage K (swizzled) ----
    {
      const short8v* src = (const short8v*)(kb + (size_t)(kg + krow) * MM + kseg * 32);
      const int base = krow * 256 + kseg * 32;
      const int sw = (krow & 7) << 3;
#pragma unroll
      for (int c = 0; c < 4; ++c) {
        short8v v = src[c];
        *(short8v*)&Ksm[(base + c * 8) ^ sw] = v;
      }
    }
    // ---- stage V transposed ----
    {
      const short8v* src = (const short8v*)(vb + (size_t)(kg + vkey) * DD + vdg * 32);
      short8v vr[4];
#pragma unroll
      for (int c = 0; c < 4; ++c) vr[c] = src[c];
#pragma unroll
      for (int c = 0; c < 4; ++c)
#pragma unroll
        for (int i = 0; i < 8; ++i)
          Vts[(vdg * 32 + c * 8 + i) * 40 + vkey] = (ushort)vr[c][i];
    }
    __syncthreads();

    // ---- S = Q @ K^T (scores pre-scaled via folded Wq) ----
    float4v sf[2][2];
#pragma unroll
    for (int rt = 0; rt < 2; ++rt)
#pragma unroll
      for (int kt = 0; kt < 2; ++kt) sf[rt][kt] = (float4v){0.f, 0.f, 0.f, 0.f};
#pragma unroll
    for (int kk = 0; kk < 8; ++kk) {
#pragma unroll
      for (int kt = 0; kt < 2; ++kt) {
        const int row = kt * 16 + lr;
        short8v kf = *(const short8v*)&Ksm[(row * 256 + kk * 32 + lg * 8) ^ ((row & 7) << 3)];
        sf[0][kt] = __builtin_amdgcn_mfma_f32_16x16x32_bf16(qfr[0][kk], kf, sf[0][kt], 0, 0, 0);
        sf[1][kt] = __builtin_amdgcn_mfma_f32_16x16x32_bf16(qfr[1][kk], kf, sf[1][kt], 0, 0, 0);
      }
    }

    // ---- online softmax (rows live in-lane; 16-lane butterflies span the cols) ----
#pragma unroll
    for (int rt = 0; rt < 2; ++rt) {
      float pm[4];
#pragma unroll
      for (int r = 0; r < 4; ++r) pm[r] = fmaxf(sf[rt][0][r], sf[rt][1][r]);
#pragma unroll
      for (int msk = 1; msk <= 8; msk <<= 1)
#pragma unroll
        for (int r = 0; r < 4; ++r) pm[r] = fmaxf(pm[r], __shfl_xor(pm[r], msk));
      bool upd = false;
#pragma unroll
      for (int r = 0; r < 4; ++r) upd |= (pm[r] > mreg[rt][r]);
      if (__any(upd)) {
#pragma unroll
        for (int r = 0; r < 4; ++r) {
          float mn = fmaxf(mreg[rt][r], pm[r]);
          float sc = __expf(mreg[rt][r] - mn);
          mreg[rt][r] = mn;
          lreg[rt][r] *= sc;
#pragma unroll
          for (int dt = 0; dt < 16; ++dt) acc[rt][dt][r] *= sc;
        }
      }
      float ps[2][4], rsum[4];
#pragma unroll
      for (int r = 0; r < 4; ++r) {
        ps[0][r] = __expf(sf[rt][0][r] - mreg[rt][r]);
        ps[1][r] = __expf(sf[rt][1][r] - mreg[rt][r]);
        rsum[r] = ps[0][r] + ps[1][r];
      }
#pragma unroll
      for (int msk = 1; msk <= 8; msk <<= 1)
#pragma unroll
        for (int r = 0; r < 4; ++r) rsum[r] += __shfl_xor(rsum[r], msk);
#pragma unroll
      for (int r = 0; r < 4; ++r) lreg[rt][r] += rsum[r];
      // write P tile (C-layout scatter -> row-major LDS)
#pragma unroll
      for (int kt = 0; kt < 2; ++kt)
#pragma unroll
        for (int r = 0; r < 4; ++r)
          Ps[wv][(rt * 16 + lg * 4 + r) * 40 + kt * 16 + lr] = f2bf(ps[kt][r]);
    }

    // ---- O += P @ V ----
    short8v pa0 = *(const short8v*)&Ps[wv][lr * 40 + lg * 8];
    short8v pa1 = *(const short8v*)&Ps[wv][(16 + lr) * 40 + lg * 8];
#pragma unroll
    for (int dt = 0; dt < 16; ++dt) {
      short8v vf = *(const short8v*)&Vts[(dt * 16 + lr) * 40 + lg * 8];
      acc[0][dt] = __builtin_amdgcn_mfma_f32_16x16x32_bf16(pa0, vf, acc[0][dt], 0, 0, 0);
      acc[1][dt] = __builtin_amdgcn_mfma_f32_16x16x32_bf16(pa1, vf, acc[1][dt], 0, 0, 0);
    }
  }

  // ---- store partial (unnormalized) + (m, l) ----
  float* op = (ks == 0) ? op0 : (ks == 1) ? op1 : (ks == 2) ? op2 : op3;
#pragma unroll
  for (int rt = 0; rt < 2; ++rt) {
#pragma unroll
    for (int r = 0; r < 4; ++r) {
      const int row = q0 + wv * 32 + rt * 16 + lg * 4 + r;
#pragma unroll
      for (int dt = 0; dt < 16; ++dt)
        op[(size_t)row * DD + dt * 16 + lr] = acc[rt][dt][r];
      if (lr == 0) ml[ks * NN + row] = make_float2(mreg[rt][r], lreg[rt][r]);
    }
  }
}

__global__ __launch_bounds__(256) void flash_merge_kernel(
    const float* __restrict__ op0, const float* __restrict__ op1,
    const float* __restrict__ op2, const float* __restrict__ op3,
    const float2* __restrict__ ml, float* __restrict__ hg)
{
  const int row = blockIdx.x;
  const int c = threadIdx.x;
  float2 e0 = ml[row], e1 = ml[NN + row], e2 = ml[2 * NN + row], e3 = ml[3 * NN + row];
  float M = fmaxf(fmaxf(e0.x, e1.x), fmaxf(e2.x, e3.x));
  float w0 = __expf(e0.x - M), w1 = __expf(e1.x - M);
  float w2 = __expf(e2.x - M), w3 = __expf(e3.x - M);
  float L = e0.y * w0 + e1.y * w1 + e2.y * w2 + e3.y * w3;
  size_t i = (size_t)row * DD + c;
  float num = op0[i] * w0 + op1[i] * w1 + op2[i] * w2 + op3[i] * w3;
  hg[i] = num / L;
}

extern "C" void kernel_launch(void* const* d_in, const int* in_sizes, int n_in,
                              void* d_out, int out_size, void* d_ws, size_t ws_size,
                              hipStream_t stream) {
  (void)in_sizes; (void)n_in; (void)out_size; (void)ws_size;
  const float* h     = (const float*)d_in[0];
  const int*   ei    = (const int*)  d_in[1];
  const float* W_gcn = (const float*)d_in[2];
  const float* b_gcn = (const float*)d_in[3];
  const float* Wq    = (const float*)d_in[4];
  const float* bq    = (const float*)d_in[5];
  const float* Wk    = (const float*)d_in[6];
  const float* bk    = (const float*)d_in[7];
  const float* Wv    = (const float*)d_in[8];
  const float* bv    = (const float*)d_in[9];
  const float* Wo    = (const float*)d_in[10];
  const float* bo    = (const float*)d_in[11];
  const float* RF    = (const float*)d_in[12];
  const float* g1    = (const float*)d_in[13];
  const float* be1   = (const float*)d_in[14];
  const float* g2    = (const float*)d_in[15];
  const float* be2   = (const float*)d_in[16];
  const float* g3    = (const float*)d_in[17];
  const float* be3   = (const float*)d_in[18];
  const float* W1    = (const float*)d_in[19];
  const float* b1    = (const float*)d_in[20];
  const float* W2    = (const float*)d_in[21];
  const float* b2    = (const float*)d_in[22];
  float* out = (float*)d_out;

  const size_t M2 = (size_t)NN * DD;  // 2M floats
  float* w = (float*)d_ws;
  float* xw  = w; w += M2;            // Opart0 during flash; hgo after
  float* h1  = w; w += M2;
  ushort* qb = (ushort*)w; w += M2 / 2;  // bf16 NN x MM
  ushort* kb = (ushort*)w; w += M2 / 2;
  ushort* vb = (ushort*)w; w += M2 / 2;
  float* hg  = w; w += M2;            // merge output; h2 after
  float* G   = w; w += 2 * M2;        // Opart2/3 during flash; FFN hidden t after
  float* RFT = w; w += DD * MM;
  float* WqRF= w; w += DD * MM;
  float* WkRF= w; w += DD * MM;
  float* bqRF= w; w += MM;
  float* bkRF= w; w += MM;
  float* mlf = w; w += (size_t)KSPLIT * NN * 2;
  float* dinv= w; w += NN;
  int* ib = (int*)w;
  int* degi    = ib; ib += NN;
  int* cursor  = ib; ib += NN;
  int* csr_off = ib; ib += NN + 4;
  int* csr_src = ib; ib += EE;

  float* op0 = xw;
  float* op1 = out;            // d_out as scratch for a flash partial
  float* op2 = G;
  float* op3 = G + M2;
  float* t   = G;              // 8192x512 FFN hidden
  float* f2  = (float*)qb;     // spans qb+kb (2M floats)
  float* h2  = hg;
  float* hgo = xw;

  // CSR build
  init_kernel<<<NN / 256, 256, 0, stream>>>(degi, cursor);
  count_kernel<<<EE / 256, 256, 0, stream>>>(ei, degi);
  scan_kernel<<<1, 1024, 0, stream>>>(degi, csr_off);
  dinv_kernel<<<NN / 256, 256, 0, stream>>>(degi, dinv);
  fill_kernel<<<EE / 256, 256, 0, stream>>>(ei, csr_off, cursor, csr_src);
  // xw = h @ W_gcn
  gemm_kernel<false,false><<<dim3(DD / 64, NN / 64), 256, 0, stream>>>(h, W_gcn, nullptr, xw, NN, DD, DD, 1.0f);
  // folded RF projections: Wq' = (Wq @ RF^T)/16, Wk' = Wk @ RF^T
  transpose_kernel<<<DD * MM / 256, 256, 0, stream>>>(RF, RFT);
  gemm_kernel<false,false><<<dim3(MM / 64, DD / 64), 256, 0, stream>>>(Wq, RFT, nullptr, WqRF, DD, DD, MM, 1.0f / 16.0f);
  gemm_kernel<false,false><<<dim3(MM / 64, DD / 64), 256, 0, stream>>>(Wk, RFT, nullptr, WkRF, DD, DD, MM, 1.0f);
  rf_bias_kernel<<<1, MM, 0, stream>>>(bq, RF, bqRF, 1.0f / 16.0f);
  rf_bias_kernel<<<1, MM, 0, stream>>>(bk, RF, bkRF, 1.0f);
  // local GCN + LN1
  gcn_gather_ln_kernel<<<NN, 256, 0, stream>>>(xw, h, dinv, csr_off, csr_src, b_gcn, g1, be1, h1);
  // projections (bf16 outputs for MFMA attention)
  gemm_kernel<false,true ><<<dim3(MM / 64, NN / 64), 256, 0, stream>>>(h1, WqRF, bqRF, (void*)qb, NN, DD, MM, 1.0f);
  gemm_kernel<false,true ><<<dim3(MM / 64, NN / 64), 256, 0, stream>>>(h1, WkRF, bkRF, (void*)kb, NN, DD, MM, 1.0f);
  gemm_kernel<false,true ><<<dim3(DD / 64, NN / 64), 256, 0, stream>>>(h1, Wv, bv, (void*)vb, NN, DD, DD, 1.0f);
  // attention (MFMA, online softmax, 4-way key split)
  flash_mfma_kernel<<<(NN / 128) * KSPLIT, 256, 0, stream>>>(qb, kb, vb, op0, op1, op2, op3, (float2*)mlf);
  flash_merge_kernel<<<NN, 256, 0, stream>>>(op0, op1, op2, op3, (const float2*)mlf, hg);
  // output projection + LN2
  gemm_kernel<false,false><<<dim3(DD / 64, NN / 64), 256, 0, stream>>>(hg, Wo, bo, hgo, NN, DD, DD, 1.0f);
  ln_res_kernel<<<NN, 256, 0, stream>>>(h1, hgo, g2, be2, h2);
  // FFN + LN3
  gemm_kernel<true ,false><<<dim3(FF / 64, NN / 64), 256, 0, stream>>>(h2, W1, b1, t, NN, DD, FF, 1.0f);
  gemm_kernel<false,false><<<dim3(DD / 64, NN / 64), 256, 0, stream>>>(t, W2, b2, f2, NN, FF, DD, 1.0f);
  ln_res_kernel<<<NN, 256, 0, stream>>>(h2, f2, g3, be3, out);
}

// Round 3
// 388.023 us; speedup vs baseline: 7.5096x; 1.4719x over previous
//
#include <hip/hip_runtime.h>
#include <hip/hip_bf16.h>

#define NN 8192
#define EE 262144
#define DD 256
#define FF 512
#define MM 256

typedef __attribute__((ext_vector_type(8))) short short8v;
typedef __attribute__((ext_vector_type(4))) float float4v;

__device__ __forceinline__ ushort f2bf(float x) {
  union { float f; unsigned u; } c; c.f = x;
  unsigned r = (c.u + 0x7FFF + ((c.u >> 16) & 1)) >> 16;
  return (ushort)r;
}
__device__ __forceinline__ float b2f(ushort u) {
  union { unsigned u; float f; } c; c.u = ((unsigned)u) << 16;
  return c.f;
}
__device__ __forceinline__ void async_copy16(void* lds, const void* g) {
  __builtin_amdgcn_global_load_lds(
      (const __attribute__((address_space(1))) void*)g,
      (__attribute__((address_space(3))) void*)lds, 16, 0, 0);
}

// ---------------- CSR build ----------------
__global__ void init_kernel(int* degi, int* cursor) {
  int i = blockIdx.x * blockDim.x + threadIdx.x;
  if (i < NN) { degi[i] = 0; cursor[i] = 0; }
}

__global__ void count_kernel(const int* __restrict__ ei, int* __restrict__ degi) {
  int i = blockIdx.x * blockDim.x + threadIdx.x;
  if (i < EE) atomicAdd(&degi[ei[EE + i]], 1);
}

__global__ __launch_bounds__(1024) void scan_kernel(const int* __restrict__ degi,
                                                    int* __restrict__ csr_off) {
  __shared__ int part[1024];
  int tid = threadIdx.x;
  int base = tid * 8;
  int loc[8]; int s = 0;
#pragma unroll
  for (int i = 0; i < 8; ++i) { loc[i] = s; s += degi[base + i]; }
  part[tid] = s;
  __syncthreads();
  for (int off = 1; off < 1024; off <<= 1) {
    int v = (tid >= off) ? part[tid - off] : 0;
    __syncthreads();
    part[tid] += v;
    __syncthreads();
  }
  int pre = (tid == 0) ? 0 : part[tid - 1];
#pragma unroll
  for (int i = 0; i < 8; ++i) csr_off[base + i] = pre + loc[i];
  if (tid == 1023) csr_off[NN] = part[1023];
}

__global__ void dinv_kernel(const int* __restrict__ degi, float* __restrict__ dinv) {
  int i = blockIdx.x * blockDim.x + threadIdx.x;
  if (i < NN) dinv[i] = rsqrtf((float)(degi[i] + 1));  // +1 = self loop
}

__global__ void fill_kernel(const int* __restrict__ ei, const int* __restrict__ csr_off,
                            int* __restrict__ cursor, int* __restrict__ csr_src) {
  int i = blockIdx.x * blockDim.x + threadIdx.x;
  if (i < EE) {
    int d = ei[EE + i];
    int pos = csr_off[d] + atomicAdd(&cursor[d], 1);
    csr_src[pos] = ei[i];
  }
}

// ---------------- converts ----------------
// fp32 [R][256] -> bf16 swizzled (col ^ ((row&7)<<3))
__global__ void f2b_sw_kernel(const float* __restrict__ src, ushort* __restrict__ dst) {
  int i = blockIdx.x * 256 + threadIdx.x;
  int row = i >> 8, col = i & 255;
  dst[(row << 8) | (col ^ ((row & 7) << 3))] = f2bf(src[i]);
}

// W [K][Nw] fp32 -> WT bf16 swizzled [Nw][K]
__global__ void wT_sw_kernel(const float* __restrict__ W, ushort* __restrict__ WT,
                             int K, int Nw) {
  int i = blockIdx.x * 256 + threadIdx.x;
  int n = i / K, k = i - n * K;
  WT[n * K + (k ^ ((n & 7) << 3))] = f2bf(W[(size_t)k * Nw + n]);
}

__global__ void transpose_kernel(const float* __restrict__ RF, float* __restrict__ RFT) {
  int i = blockIdx.x * blockDim.x + threadIdx.x;  // 65536
  int m = i >> 8, d = i & 255;
  RFT[d * MM + m] = RF[i];
}

__global__ void rf_bias_kernel(const float* __restrict__ bvec, const float* __restrict__ RF,
                               float* __restrict__ outb, float alpha) {
  int m = threadIdx.x;
  float s = 0.0f;
  for (int j = 0; j < DD; ++j) s = fmaf(bvec[j], RF[m * DD + j], s);
  outb[m] = s * alpha;
}

// ---------------- small fp32 GEMM (weights-only precompute) ----------------
template<bool RELU, bool BF16OUT>
__global__ __launch_bounds__(256) void gemm_kernel(
    const float* __restrict__ A, const float* __restrict__ B,
    const float* __restrict__ bias, void* __restrict__ Cv,
    int n, int K, int Dout, float alpha)
{
  __shared__ float As[16][68];
  __shared__ float Bs[16][68];
  const int tid = threadIdx.x;
  const int tx = tid & 15, ty = tid >> 4;
  const int n0 = blockIdx.x * 64;
  const int m0 = blockIdx.y * 64;
  float acc[4][4] = {};
  for (int k0 = 0; k0 < K; k0 += 16) {
    {
      int m = tid & 63, kq = (tid >> 6) << 2;
      float4 a4 = *reinterpret_cast<const float4*>(&A[(m0 + m) * K + k0 + kq]);
      As[kq + 0][m] = a4.x; As[kq + 1][m] = a4.y; As[kq + 2][m] = a4.z; As[kq + 3][m] = a4.w;
      int kk = tid >> 4, nn4 = (tid & 15) << 2;
      *reinterpret_cast<float4*>(&Bs[kk][nn4]) =
          *reinterpret_cast<const float4*>(&B[(k0 + kk) * Dout + n0 + nn4]);
    }
    __syncthreads();
#pragma unroll
    for (int kk = 0; kk < 16; ++kk) {
      float4 av = *reinterpret_cast<const float4*>(&As[kk][ty << 2]);
      float4 bv = *reinterpret_cast<const float4*>(&Bs[kk][tx << 2]);
      float a[4] = {av.x, av.y, av.z, av.w};
      float b[4] = {bv.x, bv.y, bv.z, bv.w};
#pragma unroll
      for (int i = 0; i < 4; ++i)
#pragma unroll
        for (int j = 0; j < 4; ++j)
          acc[i][j] = fmaf(a[i], b[j], acc[i][j]);
    }
    __syncthreads();
  }
#pragma unroll
  for (int i = 0; i < 4; ++i) {
    int row = m0 + (ty << 2) + i;
    int col = n0 + (tx << 2);
    float vals[4];
#pragma unroll
    for (int j = 0; j < 4; ++j) {
      float c = acc[i][j] * alpha + (bias ? bias[col + j] : 0.0f);
      if (RELU) c = fmaxf(c, 0.0f);
      vals[j] = c;
    }
    if (BF16OUT) {
      ushort* C = (ushort*)Cv;
#pragma unroll
      for (int j = 0; j < 4; ++j) C[(size_t)row * Dout + col + j] = f2bf(vals[j]);
    } else {
      float* C = (float*)Cv;
      *reinterpret_cast<float4*>(&C[(size_t)row * Dout + col]) =
          make_float4(vals[0], vals[1], vals[2], vals[3]);
    }
  }
}

// ---------------- MFMA GEMM: C[M][N] = act(A @ BT^T + bias) ----------------
// A [M][K] bf16 swizzled, BT [N][K] bf16 swizzled. 64x64 tile, BK=64,
// global_load_lds double-buffered with counted vmcnt.
// OMODE: 0 = f32 out, 1 = bf16 swizzled out, 2 = bf16 transposed out (C^T[n][m], unswizzled)
template<int OMODE, bool RELU>
__global__ __launch_bounds__(256) void gemm_bf16_kernel(
    const ushort* __restrict__ A, const ushort* __restrict__ BT,
    const float* __restrict__ bias, void* __restrict__ Cv,
    int M, int N, int K)
{
  __shared__ ushort As[2][4096];
  __shared__ ushort Bs[2][4096];
  const int tid = threadIdx.x;
  const int l = tid & 63;
  const int wv = tid >> 6;
  const int lr = l & 15, lg = l >> 4;
  const int m0 = blockIdx.y * 64, n0 = blockIdx.x * 64;
  const int wm = (wv >> 1) * 32, wn = (wv & 1) * 32;
  const int r0 = tid >> 3, r1 = 32 + (tid >> 3);
  const int co = (tid & 7) << 3;
  float4v acc[2][2];
#pragma unroll
  for (int mt = 0; mt < 2; ++mt)
#pragma unroll
    for (int nt = 0; nt < 2; ++nt) acc[mt][nt] = (float4v){0.f, 0.f, 0.f, 0.f};

#define GSTAGE(b, k0) { \
    async_copy16(&As[b][(r0 << 6) + co], &A[(size_t)(m0 + r0) * K + (k0) + co]); \
    async_copy16(&As[b][(r1 << 6) + co], &A[(size_t)(m0 + r1) * K + (k0) + co]); \
    async_copy16(&Bs[b][(r0 << 6) + co], &BT[(size_t)(n0 + r0) * K + (k0) + co]); \
    async_copy16(&Bs[b][(r1 << 6) + co], &BT[(size_t)(n0 + r1) * K + (k0) + co]); }

  GSTAGE(0, 0)
  const int nk = K >> 6;
  for (int kt = 0; kt < nk; ++kt) {
    if (kt + 1 < nk) {
      GSTAGE((kt + 1) & 1, (kt + 1) << 6)
      asm volatile("s_waitcnt vmcnt(4)" ::: "memory");
    } else {
      asm volatile("s_waitcnt vmcnt(0)" ::: "memory");
    }
    __syncthreads();
    const ushort* as_ = As[kt & 1];
    const ushort* bs_ = Bs[kt & 1];
    __builtin_amdgcn_s_setprio(1);
#pragma unroll
    for (int h = 0; h < 2; ++h) {
      const int swo = (((h << 2) + lg) ^ (lr & 7)) << 3;
      short8v af[2], bfr[2];
#pragma unroll
      for (int mt = 0; mt < 2; ++mt)
        af[mt] = *(const short8v*)&as_[((wm + (mt << 4) + lr) << 6) + swo];
#pragma unroll
      for (int nt = 0; nt < 2; ++nt)
        bfr[nt] = *(const short8v*)&bs_[((wn + (nt << 4) + lr) << 6) + swo];
#pragma unroll
      for (int mt = 0; mt < 2; ++mt)
#pragma unroll
        for (int nt = 0; nt < 2; ++nt)
          acc[mt][nt] = __builtin_amdgcn_mfma_f32_16x16x32_bf16(af[mt], bfr[nt], acc[mt][nt], 0, 0, 0);
    }
    __builtin_amdgcn_s_setprio(0);
    __syncthreads();
  }
#pragma unroll
  for (int nt = 0; nt < 2; ++nt) {
    const int col = n0 + wn + (nt << 4) + lr;
    const float bv = bias ? bias[col] : 0.0f;
#pragma unroll
    for (int mt = 0; mt < 2; ++mt)
#pragma unroll
      for (int r = 0; r < 4; ++r) {
        const int m = m0 + wm + (mt << 4) + (lg << 2) + r;
        float v = acc[mt][nt][r] + bv;
        if (RELU) v = fmaxf(v, 0.0f);
        if (OMODE == 0) ((float*)Cv)[(size_t)m * N + col] = v;
        else if (OMODE == 1) ((ushort*)Cv)[(size_t)m * N + (col ^ ((m & 7) << 3))] = f2bf(v);
        else ((ushort*)Cv)[(size_t)col * M + m] = f2bf(v);
      }
  }
#undef GSTAGE
}

// ---------------- GCN gather + residual + LN1 (emits fp32 + bf16sw) ----------------
__global__ __launch_bounds__(256) void gcn_gather_ln_kernel(
    const float* __restrict__ xw, const float* __restrict__ h,
    const float* __restrict__ dinv, const int* __restrict__ csr_off,
    const int* __restrict__ csr_src, const float* __restrict__ b_gcn,
    const float* __restrict__ g1, const float* __restrict__ be1,
    float* __restrict__ h1, ushort* __restrict__ h1b)
{
  __shared__ float2 red[256];
  const int node = blockIdx.x;
  const int c = threadIdx.x;
  const float di = dinv[node];
  const int e0 = csr_off[node], e1 = csr_off[node + 1];
  float acc = 0.0f;
  for (int e = e0; e < e1; ++e) {
    int s = csr_src[e];
    acc = fmaf(xw[s * DD + c], dinv[s], acc);
  }
  float y = fmaf(acc, di, xw[node * DD + c] * di * di);
  y += b_gcn[c];
  y += h[node * DD + c];
  red[c] = make_float2(y, y * y);
  __syncthreads();
  for (int sft = 128; sft > 0; sft >>= 1) {
    if (c < sft) { red[c].x += red[c + sft].x; red[c].y += red[c + sft].y; }
    __syncthreads();
  }
  float mu = red[0].x * (1.0f / 256.0f);
  float var = red[0].y * (1.0f / 256.0f) - mu * mu;
  float inv = rsqrtf(fmaxf(var, 0.0f) + 1e-5f);
  float v = (y - mu) * inv * g1[c] + be1[c];
  h1[node * DD + c] = v;
  h1b[(node << 8) | (c ^ ((node & 7) << 3))] = f2bf(v);
}

// ---------------- residual + LN (optional bf16sw copy) ----------------
__global__ __launch_bounds__(256) void ln_res_kernel(
    const float* __restrict__ a, const float* __restrict__ b,
    const float* __restrict__ g, const float* __restrict__ be,
    float* __restrict__ out, ushort* __restrict__ outb)
{
  __shared__ float2 red[256];
  const int row = blockIdx.x;
  const int c = threadIdx.x;
  float y = a[row * DD + c] + b[row * DD + c];
  red[c] = make_float2(y, y * y);
  __syncthreads();
  for (int sft = 128; sft > 0; sft >>= 1) {
    if (c < sft) { red[c].x += red[c + sft].x; red[c].y += red[c + sft].y; }
    __syncthreads();
  }
  float mu = red[0].x * (1.0f / 256.0f);
  float var = red[0].y * (1.0f / 256.0f) - mu * mu;
  float inv = rsqrtf(fmaxf(var, 0.0f) + 1e-5f);
  float v = (y - mu) * inv * g[c] + be[c];
  out[row * DD + c] = v;
  if (outb) outb[(row << 8) | (c ^ ((row & 7) << 3))] = f2bf(v);
}

// ---------------- MFMA flash attention ----------------
// 128 q-rows/block (4 waves x 32), KVBLK=32, K-split partials.
// qb/kb pre-swizzled bf16; vbT = V^T [256][NN] bf16 unswizzled.
// K/V staged via global_load_lds into double buffer, counted vmcnt(8).
__global__ __launch_bounds__(256, 2) void flash_mfma_kernel(
    const ushort* __restrict__ qb, const ushort* __restrict__ kb,
    const ushort* __restrict__ vbT, ushort* __restrict__ opb,
    float2* __restrict__ ml, int ksn, int kchunk)
{
  __shared__ ushort Kbuf[2][8192];   // [key 32][m 256] swizzled
  __shared__ ushort Vbuf[2][8192];   // [d 256][key 32]
  __shared__ ushort Ps[4][1280];     // per-wave [row 32][key 32] pad 40

  const int tid = threadIdx.x;
  const int l = tid & 63, wv = tid >> 6;
  const int lr = l & 15, lg = l >> 4;
  const int qt = blockIdx.x / ksn, ks = blockIdx.x % ksn;
  const int q0 = qt * 128;
  const int kbase = ks * kchunk;

  const int krow = tid >> 5;            // + 8c
  const int kcol = (tid & 31) << 3;
  const int vrow = tid >> 2;            // + 64c
  const int vcol = (tid & 3) << 3;

#define FSTAGE(b, kg) { \
    _Pragma("unroll") \
    for (int c = 0; c < 4; ++c) { \
      async_copy16(&Kbuf[b][((c << 8) + tid) << 3], \
                   &kb[(size_t)((kg) + (c << 3) + krow) * 256 + kcol]); \
      async_copy16(&Vbuf[b][((c << 8) + tid) << 3], \
                   &vbT[(size_t)((c << 6) + vrow) * NN + (kg) + vcol]); \
    } }

  FSTAGE(0, kbase)

  // Q fragments (32 rows x 256 feat per wave), from swizzled qb
  short8v qfr[2][8];
#pragma unroll
  for (int rt = 0; rt < 2; ++rt) {
    const int row = q0 + wv * 32 + rt * 16 + lr;
    const int sw = (row & 7) << 3;
#pragma unroll
    for (int kk = 0; kk < 8; ++kk)
      qfr[rt][kk] = *(const short8v*)&qb[(size_t)row * MM + (((kk << 5) + (lg << 3)) ^ sw)];
  }

  float4v acc[2][16];
#pragma unroll
  for (int rt = 0; rt < 2; ++rt)
#pragma unroll
    for (int dt = 0; dt < 16; ++dt) acc[rt][dt] = (float4v){0.f, 0.f, 0.f, 0.f};
  float mreg[2][4], lreg[2][4];
#pragma unroll
  for (int rt = 0; rt < 2; ++rt)
#pragma unroll
    for (int r = 0; r < 4; ++r) { mreg[rt][r] = -1e30f; lreg[rt][r] = 0.f; }

  const int nit = kchunk >> 5;
  for (int it = 0; it < nit; ++it) {
    if (it + 1 < nit) {
      FSTAGE((it + 1) & 1, kbase + ((it + 1) << 5))
      asm volatile("s_waitcnt vmcnt(8)" ::: "memory");
    } else {
      asm volatile("s_waitcnt vmcnt(0)" ::: "memory");
    }
    __syncthreads();
    const ushort* Kp = Kbuf[it & 1];
    const ushort* Vp = Vbuf[it & 1];

    // ---- S = Q @ K^T ----
    float4v sf[2][2];
#pragma unroll
    for (int rt = 0; rt < 2; ++rt)
#pragma unroll
      for (int kt = 0; kt < 2; ++kt) sf[rt][kt] = (float4v){0.f, 0.f, 0.f, 0.f};
    __builtin_amdgcn_s_setprio(1);
#pragma unroll
    for (int kk = 0; kk < 8; ++kk) {
#pragma unroll
      for (int kt = 0; kt < 2; ++kt) {
        const int row = (kt << 4) + lr;
        short8v kf = *(const short8v*)&Kp[(row << 8) + (((kk << 5) + (lg << 3)) ^ ((row & 7) << 3))];
        sf[0][kt] = __builtin_amdgcn_mfma_f32_16x16x32_bf16(qfr[0][kk], kf, sf[0][kt], 0, 0, 0);
        sf[1][kt] = __builtin_amdgcn_mfma_f32_16x16x32_bf16(qfr[1][kk], kf, sf[1][kt], 0, 0, 0);
      }
    }
    __builtin_amdgcn_s_setprio(0);

    // ---- online softmax ----
#pragma unroll
    for (int rt = 0; rt < 2; ++rt) {
      float pm[4];
#pragma unroll
      for (int r = 0; r < 4; ++r) pm[r] = fmaxf(sf[rt][0][r], sf[rt][1][r]);
#pragma unroll
      for (int msk = 1; msk <= 8; msk <<= 1)
#pragma unroll
        for (int r = 0; r < 4; ++r) pm[r] = fmaxf(pm[r], __shfl_xor(pm[r], msk));
      bool upd = false;
#pragma unroll
      for (int r = 0; r < 4; ++r) upd |= (pm[r] > mreg[rt][r]);
      if (__any(upd)) {
#pragma unroll
        for (int r = 0; r < 4; ++r) {
          float mn = fmaxf(mreg[rt][r], pm[r]);
          float sc = __expf(mreg[rt][r] - mn);
          mreg[rt][r] = mn;
          lreg[rt][r] *= sc;
#pragma unroll
          for (int dt = 0; dt < 16; ++dt) acc[rt][dt][r] *= sc;
        }
      }
      float ps[2][4], rsum[4];
#pragma unroll
      for (int r = 0; r < 4; ++r) {
        ps[0][r] = __expf(sf[rt][0][r] - mreg[rt][r]);
        ps[1][r] = __expf(sf[rt][1][r] - mreg[rt][r]);
        rsum[r] = ps[0][r] + ps[1][r];
      }
#pragma unroll
      for (int msk = 1; msk <= 8; msk <<= 1)
#pragma unroll
        for (int r = 0; r < 4; ++r) rsum[r] += __shfl_xor(rsum[r], msk);
#pragma unroll
      for (int r = 0; r < 4; ++r) lreg[rt][r] += rsum[r];
#pragma unroll
      for (int kt = 0; kt < 2; ++kt)
#pragma unroll
        for (int r = 0; r < 4; ++r)
          Ps[wv][(rt * 16 + lg * 4 + r) * 40 + kt * 16 + lr] = f2bf(ps[kt][r]);
    }

    // ---- O += P @ V ----
    short8v pa0 = *(const short8v*)&Ps[wv][lr * 40 + (lg << 3)];
    short8v pa1 = *(const short8v*)&Ps[wv][(16 + lr) * 40 + (lg << 3)];
    __builtin_amdgcn_s_setprio(1);
#pragma unroll
    for (int dt = 0; dt < 16; ++dt) {
      short8v vf = *(const short8v*)&Vp[(((dt << 4) + lr) << 5) + (lg << 3)];
      acc[0][dt] = __builtin_amdgcn_mfma_f32_16x16x32_bf16(pa0, vf, acc[0][dt], 0, 0, 0);
      acc[1][dt] = __builtin_amdgcn_mfma_f32_16x16x32_bf16(pa1, vf, acc[1][dt], 0, 0, 0);
    }
    __builtin_amdgcn_s_setprio(0);
    __syncthreads();
  }
#undef FSTAGE

  // ---- store bf16 partial (unnormalized) + (m, l) ----
  ushort* op = opb + (size_t)ks * (NN * DD);
#pragma unroll
  for (int rt = 0; rt < 2; ++rt) {
#pragma unroll
    for (int r = 0; r < 4; ++r) {
      const int row = q0 + wv * 32 + rt * 16 + lg * 4 + r;
#pragma unroll
      for (int dt = 0; dt < 16; ++dt)
        op[(size_t)row * DD + (dt << 4) + lr] = f2bf(acc[rt][dt][r]);
      if (lr == 0) ml[(size_t)ks * NN + row] = make_float2(mreg[rt][r], lreg[rt][r]);
    }
  }
}

__global__ __launch_bounds__(256) void flash_merge_kernel(
    const ushort* __restrict__ opb, const float2* __restrict__ ml,
    ushort* __restrict__ hgb, int ksn)
{
  const int row = blockIdx.x;
  const int c = threadIdx.x;
  float M = -1e30f;
  for (int i = 0; i < ksn; ++i) M = fmaxf(M, ml[(size_t)i * NN + row].x);
  float num = 0.f, L = 0.f;
  for (int i = 0; i < ksn; ++i) {
    float2 e = ml[(size_t)i * NN + row];
    float w = __expf(e.x - M);
    L += w * e.y;
    num += w * b2f(opb[(size_t)i * NN * DD + (size_t)row * DD + c]);
  }
  hgb[(row << 8) | (c ^ ((row & 7) << 3))] = f2bf(num / L);
}

extern "C" void kernel_launch(void* const* d_in, const int* in_sizes, int n_in,
                              void* d_out, int out_size, void* d_ws, size_t ws_size,
                              hipStream_t stream) {
  (void)in_sizes; (void)n_in; (void)out_size;
  const float* h     = (const float*)d_in[0];
  const int*   ei    = (const int*)  d_in[1];
  const float* W_gcn = (const float*)d_in[2];
  const float* b_gcn = (const float*)d_in[3];
  const float* Wq    = (const float*)d_in[4];
  const float* bq    = (const float*)d_in[5];
  const float* Wk    = (const float*)d_in[6];
  const float* bk    = (const float*)d_in[7];
  const float* Wv    = (const float*)d_in[8];
  const float* bv    = (const float*)d_in[9];
  const float* Wo    = (const float*)d_in[10];
  const float* bo    = (const float*)d_in[11];
  const float* RF    = (const float*)d_in[12];
  const float* g1    = (const float*)d_in[13];
  const float* be1   = (const float*)d_in[14];
  const float* g2    = (const float*)d_in[15];
  const float* be2   = (const float*)d_in[16];
  const float* g3    = (const float*)d_in[17];
  const float* be3   = (const float*)d_in[18];
  const float* W1    = (const float*)d_in[19];
  const float* b1    = (const float*)d_in[20];
  const float* W2    = (const float*)d_in[21];
  const float* b2    = (const float*)d_in[22];
  float* out = (float*)d_out;

  const size_t M2 = (size_t)NN * DD;  // 2,097,152
  const int ksn = (ws_size >= (size_t)68 * 1024 * 1024) ? 8 : 4;
  const int kchunk = NN / ksn;

  char* base = (char*)d_ws;
  float*  h1   = (float*)base;  base += M2 * 4;
  ushort* hbX  = (ushort*)base; base += M2 * 2;   // hb, later hgb
  ushort* h1bX = (ushort*)base; base += M2 * 2;   // h1b, later h2b
  ushort* qb   = (ushort*)base; base += M2 * 2;
  ushort* kb   = (ushort*)base; base += M2 * 2;
  ushort* vbT  = (ushort*)base; base += M2 * 2;
  ushort* opb  = (ushort*)base;
  float*  R    = (float*)opb;   base += (size_t)ksn * M2 * 2;
  float*  mlf  = (float*)base;  base += (size_t)8 * NN * 2 * 4;
  float*  RFT  = (float*)base;  base += DD * MM * 4;
  float*  WqRF = (float*)base;  base += DD * MM * 4;
  float*  WkRF = (float*)base;  base += DD * MM * 4;
  ushort* WgcnT = (ushort*)base; base += DD * DD * 2;
  ushort* WqRFT = (ushort*)base; base += MM * DD * 2;
  ushort* WkRFT = (ushort*)base; base += MM * DD * 2;
  ushort* WvT   = (ushort*)base; base += DD * DD * 2;
  ushort* WoT   = (ushort*)base; base += DD * DD * 2;
  ushort* W1T   = (ushort*)base; base += FF * DD * 2;
  ushort* W2T   = (ushort*)base; base += DD * FF * 2;
  float*  bqRF  = (float*)base;  base += MM * 4;
  float*  bkRF  = (float*)base;  base += MM * 4;
  float*  dinv  = (float*)base;  base += NN * 4;
  int* degi    = (int*)base; base += NN * 4;
  int* cursor  = (int*)base; base += NN * 4;
  int* csr_off = (int*)base; base += (NN + 4) * 4;
  int* csr_src = (int*)base; base += EE * 4;

  // aliases
  float*  xw  = R;                 // pre-flash
  float*  hgo = R;                 // post-merge
  float*  h2  = R + M2;            // post-merge
  ushort* tb  = qb;                // spans qb+kb, post-flash
  float*  f2  = h1;                // post-LN2
  ushort* hgb = hbX;
  ushort* h2b = h1bX;

  // CSR build
  init_kernel<<<NN / 256, 256, 0, stream>>>(degi, cursor);
  count_kernel<<<EE / 256, 256, 0, stream>>>(ei, degi);
  scan_kernel<<<1, 1024, 0, stream>>>(degi, csr_off);
  dinv_kernel<<<NN / 256, 256, 0, stream>>>(degi, dinv);
  fill_kernel<<<EE / 256, 256, 0, stream>>>(ei, csr_off, cursor, csr_src);

  // converts
  f2b_sw_kernel<<<(int)(M2 / 256), 256, 0, stream>>>(h, hbX);
  wT_sw_kernel<<<DD * DD / 256, 256, 0, stream>>>(W_gcn, WgcnT, DD, DD);
  wT_sw_kernel<<<DD * DD / 256, 256, 0, stream>>>(Wv, WvT, DD, DD);
  wT_sw_kernel<<<DD * DD / 256, 256, 0, stream>>>(Wo, WoT, DD, DD);
  wT_sw_kernel<<<DD * FF / 256, 256, 0, stream>>>(W1, W1T, DD, FF);   // -> W1T [512][256]
  wT_sw_kernel<<<FF * DD / 256, 256, 0, stream>>>(W2, W2T, FF, DD);   // -> W2T [256][512]
  transpose_kernel<<<DD * MM / 256, 256, 0, stream>>>(RF, RFT);
  gemm_kernel<false, false><<<dim3(MM / 64, DD / 64), 256, 0, stream>>>(Wq, RFT, nullptr, WqRF, DD, DD, MM, 1.0f / 16.0f);
  gemm_kernel<false, false><<<dim3(MM / 64, DD / 64), 256, 0, stream>>>(Wk, RFT, nullptr, WkRF, DD, DD, MM, 1.0f);
  rf_bias_kernel<<<1, MM, 0, stream>>>(bq, RF, bqRF, 1.0f / 16.0f);
  rf_bias_kernel<<<1, MM, 0, stream>>>(bk, RF, bkRF, 1.0f);
  wT_sw_kernel<<<DD * MM / 256, 256, 0, stream>>>(WqRF, WqRFT, DD, MM);
  wT_sw_kernel<<<DD * MM / 256, 256, 0, stream>>>(WkRF, WkRFT, DD, MM);

  // xw = h @ W_gcn  (fp32 out)
  gemm_bf16_kernel<0, false><<<dim3(DD / 64, NN / 64), 256, 0, stream>>>(hbX, WgcnT, nullptr, xw, NN, DD, DD);
  // local GCN + LN1
  gcn_gather_ln_kernel<<<NN, 256, 0, stream>>>(xw, h, dinv, csr_off, csr_src, b_gcn, g1, be1, h1, h1bX);
  // projections
  gemm_bf16_kernel<1, false><<<dim3(MM / 64, NN / 64), 256, 0, stream>>>(h1bX, WqRFT, bqRF, qb, NN, MM, DD);
  gemm_bf16_kernel<1, false><<<dim3(MM / 64, NN / 64), 256, 0, stream>>>(h1bX, WkRFT, bkRF, kb, NN, MM, DD);
  gemm_bf16_kernel<2, false><<<dim3(DD / 64, NN / 64), 256, 0, stream>>>(h1bX, WvT, bv, vbT, NN, DD, DD);
  // attention
  flash_mfma_kernel<<<(NN / 128) * ksn, 256, 0, stream>>>(qb, kb, vbT, opb, (float2*)mlf, ksn, kchunk);
  flash_merge_kernel<<<NN, 256, 0, stream>>>(opb, (const float2*)mlf, hgb, ksn);
  // output projection + LN2
  gemm_bf16_kernel<0, false><<<dim3(DD / 64, NN / 64), 256, 0, stream>>>(hgb, WoT, bo, hgo, NN, DD, DD);
  ln_res_kernel<<<NN, 256, 0, stream>>>(h1, hgo, g2, be2, h2, h2b);
  // FFN + LN3
  gemm_bf16_kernel<1, true ><<<dim3(FF / 64, NN / 64), 256, 0, stream>>>(h2b, W1T, b1, tb, NN, FF, DD);
  gemm_bf16_kernel<0, false><<<dim3(DD / 64, NN / 64), 256, 0, stream>>>(tb, W2T, b2, f2, NN, DD, FF);
  ln_res_kernel<<<NN, 256, 0, stream>>>(h2, f2, g3, be3, out, nullptr);
}

// Round 4
// 342.461 us; speedup vs baseline: 8.5086x; 1.1330x over previous
//
#include <hip/hip_runtime.h>
#include <hip/hip_bf16.h>

#define NN 8192
#define EE 262144
#define DD 256
#define FF 512
#define MM 256

typedef __attribute__((ext_vector_type(8))) short short8v;
typedef __attribute__((ext_vector_type(4))) float float4v;

__device__ __forceinline__ ushort f2bf(float x) {
  union { float f; unsigned u; } c; c.f = x;
  unsigned r = (c.u + 0x7FFF + ((c.u >> 16) & 1)) >> 16;
  return (ushort)r;
}
__device__ __forceinline__ float b2f(ushort u) {
  union { unsigned u; float f; } c; c.u = ((unsigned)u) << 16;
  return c.f;
}
__device__ __forceinline__ void async_copy16(void* lds, const void* g) {
  __builtin_amdgcn_global_load_lds(
      (const __attribute__((address_space(1))) void*)g,
      (__attribute__((address_space(3))) void*)lds, 16, 0, 0);
}

// ---------------- CSR build ----------------
__global__ void init_kernel(int* degi, int* cursor) {
  int i = blockIdx.x * blockDim.x + threadIdx.x;
  if (i < NN) { degi[i] = 0; cursor[i] = 0; }
}

__global__ void count_kernel(const int* __restrict__ ei, int* __restrict__ degi) {
  int i = blockIdx.x * blockDim.x + threadIdx.x;
  if (i < EE) atomicAdd(&degi[ei[EE + i]], 1);
}

__global__ __launch_bounds__(1024) void scan_kernel(const int* __restrict__ degi,
                                                    int* __restrict__ csr_off,
                                                    float* __restrict__ dinv) {
  __shared__ int part[1024];
  int tid = threadIdx.x;
  int base = tid * 8;
  int loc[8], dv[8]; int s = 0;
#pragma unroll
  for (int i = 0; i < 8; ++i) { int d = degi[base + i]; dv[i] = d; loc[i] = s; s += d; }
  part[tid] = s;
  __syncthreads();
  for (int off = 1; off < 1024; off <<= 1) {
    int v = (tid >= off) ? part[tid - off] : 0;
    __syncthreads();
    part[tid] += v;
    __syncthreads();
  }
  int pre = (tid == 0) ? 0 : part[tid - 1];
#pragma unroll
  for (int i = 0; i < 8; ++i) {
    csr_off[base + i] = pre + loc[i];
    dinv[base + i] = rsqrtf((float)(dv[i] + 1));  // +1 self loop
  }
  if (tid == 1023) csr_off[NN] = part[1023];
}

__global__ void fill_kernel(const int* __restrict__ ei, const int* __restrict__ csr_off,
                            int* __restrict__ cursor, int* __restrict__ csr_src) {
  int i = blockIdx.x * blockDim.x + threadIdx.x;
  if (i < EE) {
    int d = ei[EE + i];
    int pos = csr_off[d] + atomicAdd(&cursor[d], 1);
    csr_src[pos] = ei[i];
  }
}

// ---------------- fused precompute 1: all bf16-swizzle converts ----------------
__global__ __launch_bounds__(256) void prep1_kernel(
    const float* __restrict__ h, const float* __restrict__ W_gcn,
    const float* __restrict__ Wv, const float* __restrict__ Wo,
    const float* __restrict__ W1, const float* __restrict__ W2,
    const float* __restrict__ bv,
    ushort* __restrict__ hb, ushort* __restrict__ WgcnT, ushort* __restrict__ Wcat,
    ushort* __restrict__ WoT, ushort* __restrict__ W1T, ushort* __restrict__ W2T,
    float* __restrict__ bcat)
{
  int i = blockIdx.x * 256 + threadIdx.x;
  const int R0 = NN * DD;
  const int R1 = R0 + DD * DD;
  const int R2 = R1 + DD * DD;
  const int R3 = R2 + DD * DD;
  const int R4 = R3 + DD * FF;
  const int R5 = R4 + FF * DD;
  const int R6 = R5 + DD;
  if (i < R0) {
    int row = i >> 8, col = i & 255;
    hb[(row << 8) | (col ^ ((row & 7) << 3))] = f2bf(h[i]);
  } else if (i < R1) {
    int j = i - R0; int n = j >> 8, k = j & 255;
    WgcnT[(n << 8) | (k ^ ((n & 7) << 3))] = f2bf(W_gcn[k * DD + n]);
  } else if (i < R2) {
    int j = i - R1; int n = j >> 8, k = j & 255;
    Wcat[((512 + n) << 8) | (k ^ ((n & 7) << 3))] = f2bf(Wv[k * DD + n]);  // V rows of Wcat
  } else if (i < R3) {
    int j = i - R2; int n = j >> 8, k = j & 255;
    WoT[(n << 8) | (k ^ ((n & 7) << 3))] = f2bf(Wo[k * DD + n]);
  } else if (i < R4) {
    int j = i - R3; int n = j >> 8, k = j & 255;     // n<512, k<256
    W1T[(n << 8) | (k ^ ((n & 7) << 3))] = f2bf(W1[k * FF + n]);
  } else if (i < R5) {
    int j = i - R4; int n = j >> 9, k = j & 511;     // n<256, k<512
    W2T[n * FF + (k ^ ((n & 7) << 3))] = f2bf(W2[k * DD + n]);
  } else if (i < R6) {
    bcat[512 + (i - R5)] = bv[i - R5];
  }
}

// ---------------- fused precompute 2: RF folds (Wq@RF^T/16, Wk@RF^T, biases) ----------------
__global__ __launch_bounds__(256) void prep2_kernel(
    const float* __restrict__ Wq, const float* __restrict__ Wk,
    const float* __restrict__ bq, const float* __restrict__ bk,
    const float* __restrict__ RF,
    ushort* __restrict__ Wcat, float* __restrict__ bcat)
{
  __shared__ float wrow[DD];
  const int b = blockIdx.x;
  const int m = threadIdx.x;
  if (b < 512) {
    const int d = b & 255;
    const float* W = (b < 256) ? Wq : Wk;
    const float alpha = (b < 256) ? (1.0f / 16.0f) : 1.0f;
    wrow[m] = W[d * DD + m];
    __syncthreads();
    float s = 0.0f;
    for (int j = 0; j < DD; ++j) s = fmaf(RF[m * DD + j], wrow[j], s);
    s *= alpha;
    const int row = (b < 256) ? m : (256 + m);
    Wcat[(row << 8) | (d ^ ((m & 7) << 3))] = f2bf(s);
  } else {
    const float* bvec = (b == 512) ? bq : bk;
    const float alpha = (b == 512) ? (1.0f / 16.0f) : 1.0f;
    float s = 0.0f;
    for (int j = 0; j < DD; ++j) s = fmaf(bvec[j], RF[m * DD + j], s);
    bcat[((b == 512) ? 0 : 256) + m] = s * alpha;
  }
}

// ---------------- MFMA GEMM: C[M][N] = act(A @ BT^T + bias) ----------------
// A [M][K] bf16 swizzled, BT [N][K] bf16 swizzled. 64x64 tile, BK=64,
// global_load_lds double-buffered, ONE barrier per K-step.
// OMODE: 0 = f32 out; 1 = bf16 swizzled out; 3 = qkv route (Cv=qb, Cv2=kb, Cv3=vbT)
template<int OMODE, bool RELU>
__global__ __launch_bounds__(256) void gemm_bf16_kernel(
    const ushort* __restrict__ A, const ushort* __restrict__ BT,
    const float* __restrict__ bias, void* __restrict__ Cv,
    void* __restrict__ Cv2, void* __restrict__ Cv3,
    int M, int N, int K)
{
  __shared__ ushort As[2][4096];
  __shared__ ushort Bs[2][4096];
  const int tid = threadIdx.x;
  const int l = tid & 63;
  const int wv = tid >> 6;
  const int lr = l & 15, lg = l >> 4;
  const int m0 = blockIdx.y * 64, n0 = blockIdx.x * 64;
  const int wm = (wv >> 1) * 32, wn = (wv & 1) * 32;
  const int r0 = tid >> 3, r1 = 32 + (tid >> 3);
  const int co = (tid & 7) << 3;
  float4v acc[2][2];
#pragma unroll
  for (int mt = 0; mt < 2; ++mt)
#pragma unroll
    for (int nt = 0; nt < 2; ++nt) acc[mt][nt] = (float4v){0.f, 0.f, 0.f, 0.f};

#define GSTAGE(b, k0) { \
    async_copy16(&As[b][(r0 << 6) + co], &A[(size_t)(m0 + r0) * K + (k0) + co]); \
    async_copy16(&As[b][(r1 << 6) + co], &A[(size_t)(m0 + r1) * K + (k0) + co]); \
    async_copy16(&Bs[b][(r0 << 6) + co], &BT[(size_t)(n0 + r0) * K + (k0) + co]); \
    async_copy16(&Bs[b][(r1 << 6) + co], &BT[(size_t)(n0 + r1) * K + (k0) + co]); }

  GSTAGE(0, 0)
  const int nk = K >> 6;
  for (int kt = 0; kt < nk; ++kt) {
    asm volatile("s_waitcnt vmcnt(0)" ::: "memory");
    __syncthreads();
    if (kt + 1 < nk) GSTAGE((kt + 1) & 1, (kt + 1) << 6)
    const ushort* as_ = As[kt & 1];
    const ushort* bs_ = Bs[kt & 1];
    __builtin_amdgcn_s_setprio(1);
#pragma unroll
    for (int h = 0; h < 2; ++h) {
      const int swo = (((h << 2) + lg) ^ (lr & 7)) << 3;
      short8v af[2], bfr[2];
#pragma unroll
      for (int mt = 0; mt < 2; ++mt)
        af[mt] = *(const short8v*)&as_[((wm + (mt << 4) + lr) << 6) + swo];
#pragma unroll
      for (int nt = 0; nt < 2; ++nt)
        bfr[nt] = *(const short8v*)&bs_[((wn + (nt << 4) + lr) << 6) + swo];
#pragma unroll
      for (int mt = 0; mt < 2; ++mt)
#pragma unroll
        for (int nt = 0; nt < 2; ++nt)
          acc[mt][nt] = __builtin_amdgcn_mfma_f32_16x16x32_bf16(af[mt], bfr[nt], acc[mt][nt], 0, 0, 0);
    }
    __builtin_amdgcn_s_setprio(0);
  }
#pragma unroll
  for (int nt = 0; nt < 2; ++nt) {
    const int col = n0 + wn + (nt << 4) + lr;
    const float bv = bias ? bias[col] : 0.0f;
#pragma unroll
    for (int mt = 0; mt < 2; ++mt)
#pragma unroll
      for (int r = 0; r < 4; ++r) {
        const int m = m0 + wm + (mt << 4) + (lg << 2) + r;
        float v = acc[mt][nt][r] + bv;
        if (RELU) v = fmaxf(v, 0.0f);
        if (OMODE == 0) {
          ((float*)Cv)[(size_t)m * N + col] = v;
        } else if (OMODE == 1) {
          ((ushort*)Cv)[(size_t)m * N + (col ^ ((m & 7) << 3))] = f2bf(v);
        } else {  // qkv route
          if (col < 256) ((ushort*)Cv)[(size_t)m * 256 + (col ^ ((m & 7) << 3))] = f2bf(v);
          else if (col < 512) ((ushort*)Cv2)[(size_t)m * 256 + ((col - 256) ^ ((m & 7) << 3))] = f2bf(v);
          else ((ushort*)Cv3)[(size_t)(col - 512) * NN + m] = f2bf(v);
        }
      }
  }
#undef GSTAGE
}

// ---------------- GCN gather + residual + LN1 (emits fp32 + bf16sw) ----------------
__global__ __launch_bounds__(256) void gcn_gather_ln_kernel(
    const float* __restrict__ xw, const float* __restrict__ h,
    const float* __restrict__ dinv, const int* __restrict__ csr_off,
    const int* __restrict__ csr_src, const float* __restrict__ b_gcn,
    const float* __restrict__ g1, const float* __restrict__ be1,
    float* __restrict__ h1, ushort* __restrict__ h1b)
{
  __shared__ float2 red[256];
  const int node = blockIdx.x;
  const int c = threadIdx.x;
  const float di = dinv[node];
  const int e0 = csr_off[node], e1 = csr_off[node + 1];
  float acc = 0.0f;
  for (int e = e0; e < e1; ++e) {
    int s = csr_src[e];
    acc = fmaf(xw[s * DD + c], dinv[s], acc);
  }
  float y = fmaf(acc, di, xw[node * DD + c] * di * di);
  y += b_gcn[c];
  y += h[node * DD + c];
  red[c] = make_float2(y, y * y);
  __syncthreads();
  for (int sft = 128; sft > 0; sft >>= 1) {
    if (c < sft) { red[c].x += red[c + sft].x; red[c].y += red[c + sft].y; }
    __syncthreads();
  }
  float mu = red[0].x * (1.0f / 256.0f);
  float var = red[0].y * (1.0f / 256.0f) - mu * mu;
  float inv = rsqrtf(fmaxf(var, 0.0f) + 1e-5f);
  float v = (y - mu) * inv * g1[c] + be1[c];
  h1[node * DD + c] = v;
  h1b[(node << 8) | (c ^ ((node & 7) << 3))] = f2bf(v);
}

// ---------------- residual + LN ----------------
__global__ __launch_bounds__(256) void ln_res_kernel(
    const float* __restrict__ a, const float* __restrict__ b,
    const float* __restrict__ g, const float* __restrict__ be,
    float* __restrict__ out, ushort* __restrict__ outb)
{
  __shared__ float2 red[256];
  const int row = blockIdx.x;
  const int c = threadIdx.x;
  float y = a[row * DD + c] + b[row * DD + c];
  red[c] = make_float2(y, y * y);
  __syncthreads();
  for (int sft = 128; sft > 0; sft >>= 1) {
    if (c < sft) { red[c].x += red[c + sft].x; red[c].y += red[c + sft].y; }
    __syncthreads();
  }
  float mu = red[0].x * (1.0f / 256.0f);
  float var = red[0].y * (1.0f / 256.0f) - mu * mu;
  float inv = rsqrtf(fmaxf(var, 0.0f) + 1e-5f);
  float v = (y - mu) * inv * g[c] + be[c];
  out[row * DD + c] = v;
  if (outb) outb[(row << 8) | (c ^ ((row & 7) << 3))] = f2bf(v);
}

// ---------------- MFMA flash attention ----------------
// 128 q-rows/block (4 waves x 32), KVBLK=32, K-split partials.
// Single barrier per iter: vmcnt(0) -> barrier -> issue next DMA -> compute.
// Ps pad 40 + column-XOR (row bit3 -> col bit4): conflict-free P writes.
// Defer-max (thr=8) skips O-rescale on small max growth.
__global__ __launch_bounds__(256, 2) void flash_mfma_kernel(
    const ushort* __restrict__ qb, const ushort* __restrict__ kb,
    const ushort* __restrict__ vbT, ushort* __restrict__ opb,
    float2* __restrict__ ml, int ksn, int kchunk)
{
  __shared__ ushort Kbuf[2][8192];   // [key 32][m 256] swizzled
  __shared__ ushort Vbuf[2][8192];   // [d 256][key 32]
  __shared__ ushort Ps[4][1280];     // per-wave [row 32][key 32] pad 40, col-swizzled

  const int tid = threadIdx.x;
  const int l = tid & 63, wv = tid >> 6;
  const int lr = l & 15, lg = l >> 4;
  const int qt = blockIdx.x / ksn, ks = blockIdx.x % ksn;
  const int q0 = qt * 128;
  const int kbase = ks * kchunk;

  const int krow = tid >> 5;
  const int kcol = (tid & 31) << 3;
  const int vrow = tid >> 2;
  const int vcol = (tid & 3) << 3;

#define FSTAGE(b, kg) { \
    _Pragma("unroll") \
    for (int c = 0; c < 4; ++c) { \
      async_copy16(&Kbuf[b][((c << 8) + tid) << 3], \
                   &kb[(size_t)((kg) + (c << 3) + krow) * 256 + kcol]); \
      async_copy16(&Vbuf[b][((c << 8) + tid) << 3], \
                   &vbT[(size_t)((c << 6) + vrow) * NN + (kg) + vcol]); \
    } }

  FSTAGE(0, kbase)

  // Q fragments (32 rows x 256 feat per wave), from swizzled qb
  short8v qfr[2][8];
#pragma unroll
  for (int rt = 0; rt < 2; ++rt) {
    const int row = q0 + wv * 32 + rt * 16 + lr;
    const int sw = (row & 7) << 3;
#pragma unroll
    for (int kk = 0; kk < 8; ++kk)
      qfr[rt][kk] = *(const short8v*)&qb[(size_t)row * MM + (((kk << 5) + (lg << 3)) ^ sw)];
  }

  float4v acc[2][16];
#pragma unroll
  for (int rt = 0; rt < 2; ++rt)
#pragma unroll
    for (int dt = 0; dt < 16; ++dt) acc[rt][dt] = (float4v){0.f, 0.f, 0.f, 0.f};
  float mreg[2][4], lreg[2][4];
#pragma unroll
  for (int rt = 0; rt < 2; ++rt)
#pragma unroll
    for (int r = 0; r < 4; ++r) { mreg[rt][r] = -1e30f; lreg[rt][r] = 0.f; }

  const int psw = (lr >> 3) << 4;   // read-side column swizzle

  const int nit = kchunk >> 5;
  for (int it = 0; it < nit; ++it) {
    asm volatile("s_waitcnt vmcnt(0)" ::: "memory");
    __syncthreads();
    if (it + 1 < nit) FSTAGE((it + 1) & 1, kbase + ((it + 1) << 5))
    const ushort* Kp = Kbuf[it & 1];
    const ushort* Vp = Vbuf[it & 1];

    // ---- S = Q @ K^T ----
    float4v sf[2][2];
#pragma unroll
    for (int rt = 0; rt < 2; ++rt)
#pragma unroll
      for (int kt = 0; kt < 2; ++kt) sf[rt][kt] = (float4v){0.f, 0.f, 0.f, 0.f};
    __builtin_amdgcn_s_setprio(1);
#pragma unroll
    for (int kk = 0; kk < 8; ++kk) {
#pragma unroll
      for (int kt = 0; kt < 2; ++kt) {
        const int row = (kt << 4) + lr;
        short8v kf = *(const short8v*)&Kp[(row << 8) + (((kk << 5) + (lg << 3)) ^ ((row & 7) << 3))];
        sf[0][kt] = __builtin_amdgcn_mfma_f32_16x16x32_bf16(qfr[0][kk], kf, sf[0][kt], 0, 0, 0);
        sf[1][kt] = __builtin_amdgcn_mfma_f32_16x16x32_bf16(qfr[1][kk], kf, sf[1][kt], 0, 0, 0);
      }
    }
    __builtin_amdgcn_s_setprio(0);

    // ---- online softmax (defer-max, thr 8) ----
#pragma unroll
    for (int rt = 0; rt < 2; ++rt) {
      float pm[4];
#pragma unroll
      for (int r = 0; r < 4; ++r) pm[r] = fmaxf(sf[rt][0][r], sf[rt][1][r]);
#pragma unroll
      for (int msk = 1; msk <= 8; msk <<= 1)
#pragma unroll
        for (int r = 0; r < 4; ++r) pm[r] = fmaxf(pm[r], __shfl_xor(pm[r], msk));
      bool upd = false;
#pragma unroll
      for (int r = 0; r < 4; ++r) upd |= (pm[r] > mreg[rt][r] + 8.0f);
      if (__any(upd)) {
#pragma unroll
        for (int r = 0; r < 4; ++r) {
          float mn = fmaxf(mreg[rt][r], pm[r]);
          float sc = __expf(mreg[rt][r] - mn);
          mreg[rt][r] = mn;
          lreg[rt][r] *= sc;
#pragma unroll
          for (int dt = 0; dt < 16; ++dt) acc[rt][dt][r] *= sc;
        }
      }
      float ps[2][4], rsum[4];
#pragma unroll
      for (int r = 0; r < 4; ++r) {
        ps[0][r] = __expf(sf[rt][0][r] - mreg[rt][r]);
        ps[1][r] = __expf(sf[rt][1][r] - mreg[rt][r]);
        rsum[r] = ps[0][r] + ps[1][r];
      }
#pragma unroll
      for (int msk = 1; msk <= 8; msk <<= 1)
#pragma unroll
        for (int r = 0; r < 4; ++r) rsum[r] += __shfl_xor(rsum[r], msk);
#pragma unroll
      for (int r = 0; r < 4; ++r) lreg[rt][r] += rsum[r];
#pragma unroll
      for (int kt = 0; kt < 2; ++kt)
#pragma unroll
        for (int r = 0; r < 4; ++r) {
          const int prow = rt * 16 + lg * 4 + r;
          const int pcol = ((kt << 4) + lr) ^ (((prow >> 3) & 1) << 4);
          Ps[wv][prow * 40 + pcol] = f2bf(ps[kt][r]);
        }
    }

    // ---- O += P @ V ----
    short8v pa0 = *(const short8v*)&Ps[wv][lr * 40 + ((lg << 3) ^ psw)];
    short8v pa1 = *(const short8v*)&Ps[wv][(16 + lr) * 40 + ((lg << 3) ^ psw)];
    __builtin_amdgcn_s_setprio(1);
#pragma unroll
    for (int dt = 0; dt < 16; ++dt) {
      short8v vf = *(const short8v*)&Vp[(((dt << 4) + lr) << 5) + (lg << 3)];
      acc[0][dt] = __builtin_amdgcn_mfma_f32_16x16x32_bf16(pa0, vf, acc[0][dt], 0, 0, 0);
      acc[1][dt] = __builtin_amdgcn_mfma_f32_16x16x32_bf16(pa1, vf, acc[1][dt], 0, 0, 0);
    }
    __builtin_amdgcn_s_setprio(0);
  }
#undef FSTAGE

  // ---- store bf16 partial (unnormalized) + (m, l) ----
  ushort* op = opb + (size_t)ks * (NN * DD);
#pragma unroll
  for (int rt = 0; rt < 2; ++rt) {
#pragma unroll
    for (int r = 0; r < 4; ++r) {
      const int row = q0 + wv * 32 + rt * 16 + lg * 4 + r;
#pragma unroll
      for (int dt = 0; dt < 16; ++dt)
        op[(size_t)row * DD + (dt << 4) + lr] = f2bf(acc[rt][dt][r]);
      if (lr == 0) ml[(size_t)ks * NN + row] = make_float2(mreg[rt][r], lreg[rt][r]);
    }
  }
}

__global__ __launch_bounds__(256) void flash_merge_kernel(
    const ushort* __restrict__ opb, const float2* __restrict__ ml,
    ushort* __restrict__ hgb, int ksn)
{
  const int row = blockIdx.x;
  const int c = threadIdx.x;
  float M = -1e30f;
  for (int i = 0; i < ksn; ++i) M = fmaxf(M, ml[(size_t)i * NN + row].x);
  float num = 0.f, L = 0.f;
  for (int i = 0; i < ksn; ++i) {
    float2 e = ml[(size_t)i * NN + row];
    float w = __expf(e.x - M);
    L += w * e.y;
    num += w * b2f(opb[(size_t)i * NN * DD + (size_t)row * DD + c]);
  }
  hgb[(row << 8) | (c ^ ((row & 7) << 3))] = f2bf(num / L);
}

extern "C" void kernel_launch(void* const* d_in, const int* in_sizes, int n_in,
                              void* d_out, int out_size, void* d_ws, size_t ws_size,
                              hipStream_t stream) {
  (void)in_sizes; (void)n_in; (void)out_size;
  const float* h     = (const float*)d_in[0];
  const int*   ei    = (const int*)  d_in[1];
  const float* W_gcn = (const float*)d_in[2];
  const float* b_gcn = (const float*)d_in[3];
  const float* Wq    = (const float*)d_in[4];
  const float* bq    = (const float*)d_in[5];
  const float* Wk    = (const float*)d_in[6];
  const float* bk    = (const float*)d_in[7];
  const float* Wv    = (const float*)d_in[8];
  const float* bv    = (const float*)d_in[9];
  const float* Wo    = (const float*)d_in[10];
  const float* bo    = (const float*)d_in[11];
  const float* RF    = (const float*)d_in[12];
  const float* g1    = (const float*)d_in[13];
  const float* be1   = (const float*)d_in[14];
  const float* g2    = (const float*)d_in[15];
  const float* be2   = (const float*)d_in[16];
  const float* g3    = (const float*)d_in[17];
  const float* be3   = (const float*)d_in[18];
  const float* W1    = (const float*)d_in[19];
  const float* b1    = (const float*)d_in[20];
  const float* W2    = (const float*)d_in[21];
  const float* b2    = (const float*)d_in[22];
  float* out = (float*)d_out;

  const size_t M2 = (size_t)NN * DD;
  const int ksn = (ws_size >= (size_t)64 * 1024 * 1024) ? 8 : 4;
  const int kchunk = NN / ksn;

  char* base = (char*)d_ws;
  float*  h1   = (float*)base;  base += M2 * 4;
  ushort* hbX  = (ushort*)base; base += M2 * 2;   // hb, later hgb
  ushort* h1bX = (ushort*)base; base += M2 * 2;   // h1b, later h2b
  ushort* qb   = (ushort*)base; base += M2 * 2;
  ushort* kb   = (ushort*)base; base += M2 * 2;
  ushort* vbT  = (ushort*)base; base += M2 * 2;
  ushort* opb  = (ushort*)base;
  float*  R    = (float*)opb;   base += (size_t)ksn * M2 * 2;
  float*  mlf  = (float*)base;  base += (size_t)8 * NN * 2 * 4;
  ushort* WgcnT = (ushort*)base; base += DD * DD * 2;
  ushort* Wcat  = (ushort*)base; base += (size_t)768 * DD * 2;
  ushort* WoT   = (ushort*)base; base += DD * DD * 2;
  ushort* W1T   = (ushort*)base; base += FF * DD * 2;
  ushort* W2T   = (ushort*)base; base += DD * FF * 2;
  float*  bcat  = (float*)base;  base += 768 * 4;
  float*  dinv  = (float*)base;  base += NN * 4;
  int* degi    = (int*)base; base += NN * 4;
  int* cursor  = (int*)base; base += NN * 4;
  int* csr_off = (int*)base; base += (NN + 4) * 4;
  int* csr_src = (int*)base; base += EE * 4;

  // aliases
  float*  xw  = R;                 // pre-flash
  float*  hgo = R;                 // post-merge
  float*  h2  = R + M2;            // post-merge
  ushort* tb  = qb;                // spans qb+kb, post-flash (8192x512 bf16)
  float*  f2  = h1;                // post-LN2 (h1 dead after LN2)
  ushort* hgb = hbX;
  ushort* h2b = h1bX;

  // CSR build
  init_kernel<<<NN / 256, 256, 0, stream>>>(degi, cursor);
  count_kernel<<<EE / 256, 256, 0, stream>>>(ei, degi);
  scan_kernel<<<1, 1024, 0, stream>>>(degi, csr_off, dinv);
  fill_kernel<<<EE / 256, 256, 0, stream>>>(ei, csr_off, cursor, csr_src);

  // precompute (fused)
  {
    const int total = NN * DD + 3 * DD * DD + 2 * DD * FF + DD;
    prep1_kernel<<<(total + 255) / 256, 256, 0, stream>>>(
        h, W_gcn, Wv, Wo, W1, W2, bv, hbX, WgcnT, Wcat, WoT, W1T, W2T, bcat);
  }
  prep2_kernel<<<514, 256, 0, stream>>>(Wq, Wk, bq, bk, RF, Wcat, bcat);

  // xw = h @ W_gcn (fp32 out)
  gemm_bf16_kernel<0, false><<<dim3(DD / 64, NN / 64), 256, 0, stream>>>(
      hbX, WgcnT, nullptr, xw, nullptr, nullptr, NN, DD, DD);
  // local GCN + LN1
  gcn_gather_ln_kernel<<<NN, 256, 0, stream>>>(xw, h, dinv, csr_off, csr_src, b_gcn, g1, be1, h1, h1bX);
  // fused q/k/v projections (single GEMM, routed epilogue)
  gemm_bf16_kernel<3, false><<<dim3(768 / 64, NN / 64), 256, 0, stream>>>(
      h1bX, Wcat, bcat, qb, kb, vbT, NN, 768, DD);
  // attention
  flash_mfma_kernel<<<(NN / 128) * ksn, 256, 0, stream>>>(qb, kb, vbT, opb, (float2*)mlf, ksn, kchunk);
  flash_merge_kernel<<<NN, 256, 0, stream>>>(opb, (const float2*)mlf, hgb, ksn);
  // output projection + LN2
  gemm_bf16_kernel<0, false><<<dim3(DD / 64, NN / 64), 256, 0, stream>>>(
      hgb, WoT, bo, hgo, nullptr, nullptr, NN, DD, DD);
  ln_res_kernel<<<NN, 256, 0, stream>>>(h1, hgo, g2, be2, h2, h2b);
  // FFN + LN3
  gemm_bf16_kernel<1, true ><<<dim3(FF / 64, NN / 64), 256, 0, stream>>>(
      h2b, W1T, b1, tb, nullptr, nullptr, NN, FF, DD);
  gemm_bf16_kernel<0, false><<<dim3(DD / 64, NN / 64), 256, 0, stream>>>(
      tb, W2T, b2, f2, nullptr, nullptr, NN, DD, FF);
  ln_res_kernel<<<NN, 256, 0, stream>>>(h2, f2, g3, be3, out, nullptr);
}

// Round 5
// 300.660 us; speedup vs baseline: 9.6916x; 1.1390x over previous
//
#include <hip/hip_runtime.h>
#include <hip/hip_bf16.h>

#define NN 8192
#define EE 262144
#define DD 256
#define FF 512
#define MM 256

typedef __attribute__((ext_vector_type(8))) short short8v;
typedef __attribute__((ext_vector_type(4))) float float4v;

__device__ __forceinline__ ushort f2bf(float x) {
  union { float f; unsigned u; } c; c.f = x;
  unsigned r = (c.u + 0x7FFF + ((c.u >> 16) & 1)) >> 16;
  return (ushort)r;
}
__device__ __forceinline__ float b2f(ushort u) {
  union { unsigned u; float f; } c; c.u = ((unsigned)u) << 16;
  return c.f;
}
__device__ __forceinline__ unsigned pk2(float lo, float hi) {
  return (unsigned)f2bf(lo) | ((unsigned)f2bf(hi) << 16);
}
__device__ __forceinline__ void async_copy16(void* lds, const void* g) {
  __builtin_amdgcn_global_load_lds(
      (const __attribute__((address_space(1))) void*)g,
      (__attribute__((address_space(3))) void*)lds, 16, 0, 0);
}

// ---------------- CSR build ----------------
__global__ void init_kernel(int* degi, int* cursor) {
  int i = blockIdx.x * blockDim.x + threadIdx.x;
  if (i < NN) { degi[i] = 0; cursor[i] = 0; }
}

__global__ void count_kernel(const int* __restrict__ ei, int* __restrict__ degi) {
  int i = blockIdx.x * blockDim.x + threadIdx.x;
  if (i < EE) atomicAdd(&degi[ei[EE + i]], 1);
}

__global__ __launch_bounds__(1024) void scan_kernel(const int* __restrict__ degi,
                                                    int* __restrict__ csr_off,
                                                    float* __restrict__ dinv) {
  __shared__ int part[1024];
  int tid = threadIdx.x;
  int base = tid * 8;
  int loc[8], dv[8]; int s = 0;
#pragma unroll
  for (int i = 0; i < 8; ++i) { int d = degi[base + i]; dv[i] = d; loc[i] = s; s += d; }
  part[tid] = s;
  __syncthreads();
  for (int off = 1; off < 1024; off <<= 1) {
    int v = (tid >= off) ? part[tid - off] : 0;
    __syncthreads();
    part[tid] += v;
    __syncthreads();
  }
  int pre = (tid == 0) ? 0 : part[tid - 1];
#pragma unroll
  for (int i = 0; i < 8; ++i) {
    csr_off[base + i] = pre + loc[i];
    dinv[base + i] = rsqrtf((float)(dv[i] + 1));  // +1 self loop
  }
  if (tid == 1023) csr_off[NN] = part[1023];
}

__global__ void fill_kernel(const int* __restrict__ ei, const int* __restrict__ csr_off,
                            int* __restrict__ cursor, int* __restrict__ csr_src) {
  int i = blockIdx.x * blockDim.x + threadIdx.x;
  if (i < EE) {
    int d = ei[EE + i];
    int pos = csr_off[d] + atomicAdd(&cursor[d], 1);
    csr_src[pos] = ei[i];
  }
}

// ---------------- fused precompute 1: all bf16-swizzle converts ----------------
__global__ __launch_bounds__(256) void prep1_kernel(
    const float* __restrict__ h, const float* __restrict__ W_gcn,
    const float* __restrict__ Wv, const float* __restrict__ Wo,
    const float* __restrict__ W1, const float* __restrict__ W2,
    const float* __restrict__ bv,
    ushort* __restrict__ hb, ushort* __restrict__ WgcnT, ushort* __restrict__ Wcat,
    ushort* __restrict__ WoT, ushort* __restrict__ W1T, ushort* __restrict__ W2T,
    float* __restrict__ bcat)
{
  int i = blockIdx.x * 256 + threadIdx.x;
  const int R0 = NN * DD;
  const int R1 = R0 + DD * DD;
  const int R2 = R1 + DD * DD;
  const int R3 = R2 + DD * DD;
  const int R4 = R3 + DD * FF;
  const int R5 = R4 + FF * DD;
  const int R6 = R5 + DD;
  if (i < R0) {
    int row = i >> 8, col = i & 255;
    hb[(row << 8) | (col ^ ((row & 7) << 3))] = f2bf(h[i]);
  } else if (i < R1) {
    int j = i - R0; int n = j >> 8, k = j & 255;
    WgcnT[(n << 8) | (k ^ ((n & 7) << 3))] = f2bf(W_gcn[k * DD + n]);
  } else if (i < R2) {
    int j = i - R1; int n = j >> 8, k = j & 255;
    Wcat[((512 + n) << 8) | (k ^ ((n & 7) << 3))] = f2bf(Wv[k * DD + n]);  // V rows of Wcat
  } else if (i < R3) {
    int j = i - R2; int n = j >> 8, k = j & 255;
    WoT[(n << 8) | (k ^ ((n & 7) << 3))] = f2bf(Wo[k * DD + n]);
  } else if (i < R4) {
    int j = i - R3; int n = j >> 8, k = j & 255;     // n<512, k<256
    W1T[(n << 8) | (k ^ ((n & 7) << 3))] = f2bf(W1[k * FF + n]);
  } else if (i < R5) {
    int j = i - R4; int n = j >> 9, k = j & 511;     // n<256, k<512
    W2T[n * FF + (k ^ ((n & 7) << 3))] = f2bf(W2[k * DD + n]);
  } else if (i < R6) {
    bcat[512 + (i - R5)] = bv[i - R5];
  }
}

// ---------------- fused precompute 2: RF folds. Q side scaled by log2(e)/16 ----------------
#define QSCALE 0.090168441f   // log2(e) / 16
__global__ __launch_bounds__(256) void prep2_kernel(
    const float* __restrict__ Wq, const float* __restrict__ Wk,
    const float* __restrict__ bq, const float* __restrict__ bk,
    const float* __restrict__ RF,
    ushort* __restrict__ Wcat, float* __restrict__ bcat)
{
  __shared__ float wrow[DD];
  const int b = blockIdx.x;
  const int m = threadIdx.x;
  if (b < 512) {
    const int d = b & 255;
    const float* W = (b < 256) ? Wq : Wk;
    const float alpha = (b < 256) ? QSCALE : 1.0f;
    wrow[m] = W[d * DD + m];
    __syncthreads();
    float s = 0.0f;
    for (int j = 0; j < DD; ++j) s = fmaf(RF[m * DD + j], wrow[j], s);
    s *= alpha;
    const int row = (b < 256) ? m : (256 + m);
    Wcat[(row << 8) | (d ^ ((m & 7) << 3))] = f2bf(s);
  } else {
    const float* bvec = (b == 512) ? bq : bk;
    const float alpha = (b == 512) ? QSCALE : 1.0f;
    float s = 0.0f;
    for (int j = 0; j < DD; ++j) s = fmaf(bvec[j], RF[m * DD + j], s);
    bcat[((b == 512) ? 0 : 256) + m] = s * alpha;
  }
}

// ---------------- MFMA GEMM: C[M][N] = act(A @ BT^T + bias) ----------------
// OMODE: 0 = f32 out; 1 = bf16 swizzled; 3 = qkv route; 4 = bf16 plain
template<int OMODE, bool RELU>
__global__ __launch_bounds__(256) void gemm_bf16_kernel(
    const ushort* __restrict__ A, const ushort* __restrict__ BT,
    const float* __restrict__ bias, void* __restrict__ Cv,
    void* __restrict__ Cv2, void* __restrict__ Cv3,
    int M, int N, int K)
{
  __shared__ ushort As[2][4096];
  __shared__ ushort Bs[2][4096];
  const int tid = threadIdx.x;
  const int l = tid & 63;
  const int wv = tid >> 6;
  const int lr = l & 15, lg = l >> 4;
  const int m0 = blockIdx.y * 64, n0 = blockIdx.x * 64;
  const int wm = (wv >> 1) * 32, wn = (wv & 1) * 32;
  const int r0 = tid >> 3, r1 = 32 + (tid >> 3);
  const int co = (tid & 7) << 3;
  float4v acc[2][2];
#pragma unroll
  for (int mt = 0; mt < 2; ++mt)
#pragma unroll
    for (int nt = 0; nt < 2; ++nt) acc[mt][nt] = (float4v){0.f, 0.f, 0.f, 0.f};

#define GSTAGE(b, k0) { \
    async_copy16(&As[b][(r0 << 6) + co], &A[(size_t)(m0 + r0) * K + (k0) + co]); \
    async_copy16(&As[b][(r1 << 6) + co], &A[(size_t)(m0 + r1) * K + (k0) + co]); \
    async_copy16(&Bs[b][(r0 << 6) + co], &BT[(size_t)(n0 + r0) * K + (k0) + co]); \
    async_copy16(&Bs[b][(r1 << 6) + co], &BT[(size_t)(n0 + r1) * K + (k0) + co]); }

  GSTAGE(0, 0)
  const int nk = K >> 6;
  for (int kt = 0; kt < nk; ++kt) {
    asm volatile("s_waitcnt vmcnt(0)" ::: "memory");
    __syncthreads();
    if (kt + 1 < nk) GSTAGE((kt + 1) & 1, (kt + 1) << 6)
    const ushort* as_ = As[kt & 1];
    const ushort* bs_ = Bs[kt & 1];
    __builtin_amdgcn_s_setprio(1);
#pragma unroll
    for (int h = 0; h < 2; ++h) {
      const int swo = (((h << 2) + lg) ^ (lr & 7)) << 3;
      short8v af[2], bfr[2];
#pragma unroll
      for (int mt = 0; mt < 2; ++mt)
        af[mt] = *(const short8v*)&as_[((wm + (mt << 4) + lr) << 6) + swo];
#pragma unroll
      for (int nt = 0; nt < 2; ++nt)
        bfr[nt] = *(const short8v*)&bs_[((wn + (nt << 4) + lr) << 6) + swo];
#pragma unroll
      for (int mt = 0; mt < 2; ++mt)
#pragma unroll
        for (int nt = 0; nt < 2; ++nt)
          acc[mt][nt] = __builtin_amdgcn_mfma_f32_16x16x32_bf16(af[mt], bfr[nt], acc[mt][nt], 0, 0, 0);
    }
    __builtin_amdgcn_s_setprio(0);
  }
#pragma unroll
  for (int nt = 0; nt < 2; ++nt) {
    const int col = n0 + wn + (nt << 4) + lr;
    const float bv = bias ? bias[col] : 0.0f;
#pragma unroll
    for (int mt = 0; mt < 2; ++mt)
#pragma unroll
      for (int r = 0; r < 4; ++r) {
        const int m = m0 + wm + (mt << 4) + (lg << 2) + r;
        float v = acc[mt][nt][r] + bv;
        if (RELU) v = fmaxf(v, 0.0f);
        if (OMODE == 0) {
          ((float*)Cv)[(size_t)m * N + col] = v;
        } else if (OMODE == 1) {
          ((ushort*)Cv)[(size_t)m * N + (col ^ ((m & 7) << 3))] = f2bf(v);
        } else if (OMODE == 4) {
          ((ushort*)Cv)[(size_t)m * N + col] = f2bf(v);
        } else {  // qkv route
          if (col < 256) ((ushort*)Cv)[(size_t)m * 256 + (col ^ ((m & 7) << 3))] = f2bf(v);
          else if (col < 512) ((ushort*)Cv2)[(size_t)m * 256 + ((col - 256) ^ ((m & 7) << 3))] = f2bf(v);
          else ((ushort*)Cv3)[(size_t)(col - 512) * NN + m] = f2bf(v);
        }
      }
  }
#undef GSTAGE
}

// ---------------- GCN gather + residual + LN1 (xw in bf16) ----------------
__global__ __launch_bounds__(256) void gcn_gather_ln_kernel(
    const ushort* __restrict__ xwb, const float* __restrict__ h,
    const float* __restrict__ dinv, const int* __restrict__ csr_off,
    const int* __restrict__ csr_src, const float* __restrict__ b_gcn,
    const float* __restrict__ g1, const float* __restrict__ be1,
    float* __restrict__ h1, ushort* __restrict__ h1b)
{
  __shared__ float2 red[256];
  const int node = blockIdx.x;
  const int c = threadIdx.x;
  const float di = dinv[node];
  const int e0 = csr_off[node], e1 = csr_off[node + 1];
  float acc = 0.0f;
  for (int e = e0; e < e1; ++e) {
    int s = csr_src[e];
    acc = fmaf(b2f(xwb[(size_t)s * DD + c]), dinv[s], acc);
  }
  float y = fmaf(acc, di, b2f(xwb[(size_t)node * DD + c]) * di * di);
  y += b_gcn[c];
  y += h[node * DD + c];
  red[c] = make_float2(y, y * y);
  __syncthreads();
  for (int sft = 128; sft > 0; sft >>= 1) {
    if (c < sft) { red[c].x += red[c + sft].x; red[c].y += red[c + sft].y; }
    __syncthreads();
  }
  float mu = red[0].x * (1.0f / 256.0f);
  float var = red[0].y * (1.0f / 256.0f) - mu * mu;
  float inv = rsqrtf(fmaxf(var, 0.0f) + 1e-5f);
  float v = (y - mu) * inv * g1[c] + be1[c];
  h1[node * DD + c] = v;
  h1b[(node << 8) | (c ^ ((node & 7) << 3))] = f2bf(v);
}

// ---------------- residual + LN ----------------
__global__ __launch_bounds__(256) void ln_res_kernel(
    const float* __restrict__ a, const float* __restrict__ b,
    const float* __restrict__ g, const float* __restrict__ be,
    float* __restrict__ out, ushort* __restrict__ outb)
{
  __shared__ float2 red[256];
  const int row = blockIdx.x;
  const int c = threadIdx.x;
  float y = a[row * DD + c] + b[row * DD + c];
  red[c] = make_float2(y, y * y);
  __syncthreads();
  for (int sft = 128; sft > 0; sft >>= 1) {
    if (c < sft) { red[c].x += red[c + sft].x; red[c].y += red[c + sft].y; }
    __syncthreads();
  }
  float mu = red[0].x * (1.0f / 256.0f);
  float var = red[0].y * (1.0f / 256.0f) - mu * mu;
  float inv = rsqrtf(fmaxf(var, 0.0f) + 1e-5f);
  float v = (y - mu) * inv * g[c] + be[c];
  out[row * DD + c] = v;
  if (outb) outb[(row << 8) | (c ^ ((row & 7) << 3))] = f2bf(v);
}

// ---------------- MFMA flash attention (swapped QK^T, in-register softmax) ----------------
// 128 q-rows/block (4 waves x 32). Scores computed as S^T = mfma(K, Q): each lane
// holds 8 scores of ONE q-row (lr) -> softmax is in-lane + 2 shfl_xor. P reaches
// PV's A-frag via 16 __shfl (no LDS round-trip). V LDS slot-XOR'ed via global
// pre-swizzle (rule 21) so PV ds_read_b128 is conflict-free. Log2-domain exps.
__global__ __launch_bounds__(256, 2) void flash_mfma_kernel(
    const ushort* __restrict__ qb, const ushort* __restrict__ kb,
    const ushort* __restrict__ vbT, ushort* __restrict__ opb,
    float2* __restrict__ ml, int ksn, int kchunk)
{
  __shared__ ushort Kbuf[2][8192];   // [key 32][m 256] swizzled
  __shared__ ushort Vbuf[2][8192];   // [d 256][key 32], 16B-slot ^ ((d>>1)&3)

  const int tid = threadIdx.x;
  const int l = tid & 63, wv = tid >> 6;
  const int lr = l & 15, lg = l >> 4;
  const int qt = blockIdx.x / ksn, ks = blockIdx.x % ksn;  // ks = bid%8 -> per-XCD KV chunk
  const int q0 = qt * 128;
  const int kbase = ks * kchunk;

  const int krow = tid >> 5;
  const int kcol = (tid & 31) << 3;
  const int vrow = tid >> 2;
  const int vcolsw = (((tid & 3) ^ ((vrow >> 1) & 3)) << 3);  // inverse slot swizzle on source

#define FSTAGE(b, kg) { \
    _Pragma("unroll") \
    for (int c = 0; c < 4; ++c) { \
      async_copy16(&Kbuf[b][((c << 8) + tid) << 3], \
                   &kb[(size_t)((kg) + (c << 3) + krow) * 256 + kcol]); \
      async_copy16(&Vbuf[b][((c << 8) + tid) << 3], \
                   &vbT[(size_t)((c << 6) + vrow) * NN + (kg) + vcolsw]); \
    } }

  FSTAGE(0, kbase)

  // Q fragments (32 rows x 256 feat per wave), from swizzled qb
  short8v qfr[2][8];
#pragma unroll
  for (int rt = 0; rt < 2; ++rt) {
    const int row = q0 + wv * 32 + rt * 16 + lr;
    const int sw = (row & 7) << 3;
#pragma unroll
    for (int kk = 0; kk < 8; ++kk)
      qfr[rt][kk] = *(const short8v*)&qb[(size_t)row * MM + (((kk << 5) + (lg << 3)) ^ sw)];
  }

  float4v acc[2][16];
#pragma unroll
  for (int rt = 0; rt < 2; ++rt)
#pragma unroll
    for (int dt = 0; dt < 16; ++dt) acc[rt][dt] = (float4v){0.f, 0.f, 0.f, 0.f};
  float mreg[2] = {-1e30f, -1e30f};
  float lreg[2] = {0.f, 0.f};

  const int vsw = (lg ^ ((lr >> 1) & 3)) << 3;  // read-side V slot swizzle
  const int L0 = lr + ((lg & 1) << 5);          // P-shuffle source lanes
  const int L1 = L0 + 16;
  const bool hik = (lg >= 2);

  const int nit = kchunk >> 5;
  for (int it = 0; it < nit; ++it) {
    asm volatile("s_waitcnt vmcnt(0)" ::: "memory");
    __syncthreads();
    if (it + 1 < nit) FSTAGE((it + 1) & 1, kbase + ((it + 1) << 5))
    const ushort* Kp = Kbuf[it & 1];
    const ushort* Vp = Vbuf[it & 1];

    // ---- S^T = K @ Q^T ----
    float4v sf[2][2];  // [rt][kt]
#pragma unroll
    for (int rt = 0; rt < 2; ++rt)
#pragma unroll
      for (int kt = 0; kt < 2; ++kt) sf[rt][kt] = (float4v){0.f, 0.f, 0.f, 0.f};
    __builtin_amdgcn_s_setprio(1);
#pragma unroll
    for (int kk = 0; kk < 8; ++kk) {
#pragma unroll
      for (int kt = 0; kt < 2; ++kt) {
        const int row = (kt << 4) + lr;
        short8v kf = *(const short8v*)&Kp[(row << 8) + (((kk << 5) + (lg << 3)) ^ ((row & 7) << 3))];
        sf[0][kt] = __builtin_amdgcn_mfma_f32_16x16x32_bf16(kf, qfr[0][kk], sf[0][kt], 0, 0, 0);
        sf[1][kt] = __builtin_amdgcn_mfma_f32_16x16x32_bf16(kf, qfr[1][kk], sf[1][kt], 0, 0, 0);
      }
    }
    __builtin_amdgcn_s_setprio(0);

    // ---- softmax (in-lane, log2 domain, defer-max) + P redistribution ----
    short8v pa[2];
#pragma unroll
    for (int rt = 0; rt < 2; ++rt) {
      float4v a = sf[rt][0], b = sf[rt][1];
      float pm = fmaxf(fmaxf(fmaxf(a[0], a[1]), fmaxf(a[2], a[3])),
                       fmaxf(fmaxf(b[0], b[1]), fmaxf(b[2], b[3])));
      pm = fmaxf(pm, __shfl_xor(pm, 16));
      pm = fmaxf(pm, __shfl_xor(pm, 32));
      if (__any(pm > mreg[rt] + 11.0f)) {
        float mn = fmaxf(mreg[rt], pm);
        float sc = exp2f(mreg[rt] - mn);
        mreg[rt] = mn;
        lreg[rt] *= sc;
        float s0 = __shfl(sc, (lg << 2) | 0);
        float s1 = __shfl(sc, (lg << 2) | 1);
        float s2 = __shfl(sc, (lg << 2) | 2);
        float s3 = __shfl(sc, (lg << 2) | 3);
#pragma unroll
        for (int dt = 0; dt < 16; ++dt) {
          acc[rt][dt][0] *= s0; acc[rt][dt][1] *= s1;
          acc[rt][dt][2] *= s2; acc[rt][dt][3] *= s3;
        }
      }
      float p0[4], p1[4];
      float rs = 0.f;
#pragma unroll
      for (int r = 0; r < 4; ++r) {
        p0[r] = exp2f(a[r] - mreg[rt]);
        p1[r] = exp2f(b[r] - mreg[rt]);
        rs += p0[r] + p1[r];
      }
      rs += __shfl_xor(rs, 16);
      rs += __shfl_xor(rs, 32);
      lreg[rt] += rs;
      unsigned A0 = pk2(p0[0], p0[1]), A1 = pk2(p0[2], p0[3]);
      unsigned B0 = pk2(p1[0], p1[1]), B1 = pk2(p1[2], p1[3]);
      unsigned a0 = __shfl(A0, L0), a1 = __shfl(A1, L0);
      unsigned a2 = __shfl(A0, L1), a3 = __shfl(A1, L1);
      unsigned c0 = __shfl(B0, L0), c1 = __shfl(B1, L0);
      unsigned c2 = __shfl(B0, L1), c3 = __shfl(B1, L1);
      union { unsigned u[4]; short8v v; } pu;
      pu.u[0] = hik ? c0 : a0;
      pu.u[1] = hik ? c1 : a1;
      pu.u[2] = hik ? c2 : a2;
      pu.u[3] = hik ? c3 : a3;
      pa[rt] = pu.v;
    }

    // ---- O += P @ V ----
    __builtin_amdgcn_s_setprio(1);
#pragma unroll
    for (int dt = 0; dt < 16; ++dt) {
      short8v vf = *(const short8v*)&Vp[(((dt << 4) + lr) << 5) + vsw];
      acc[0][dt] = __builtin_amdgcn_mfma_f32_16x16x32_bf16(pa[0], vf, acc[0][dt], 0, 0, 0);
      acc[1][dt] = __builtin_amdgcn_mfma_f32_16x16x32_bf16(pa[1], vf, acc[1][dt], 0, 0, 0);
    }
    __builtin_amdgcn_s_setprio(0);
  }
#undef FSTAGE

  // ---- store bf16 partial (unnormalized) + (m, l) ----
  ushort* op = opb + (size_t)ks * (NN * DD);
#pragma unroll
  for (int rt = 0; rt < 2; ++rt) {
    if (lg == 0)
      ml[(size_t)ks * NN + q0 + wv * 32 + rt * 16 + lr] = make_float2(mreg[rt], lreg[rt]);
#pragma unroll
    for (int r = 0; r < 4; ++r) {
      const int row = q0 + wv * 32 + rt * 16 + (lg << 2) + r;
#pragma unroll
      for (int dt = 0; dt < 16; ++dt)
        op[(size_t)row * DD + (dt << 4) + lr] = f2bf(acc[rt][dt][r]);
    }
  }
}

__global__ __launch_bounds__(256) void flash_merge_kernel(
    const ushort* __restrict__ opb, const float2* __restrict__ ml,
    ushort* __restrict__ hgb, int ksn)
{
  const int row = blockIdx.x;
  const int c = threadIdx.x;
  float M = -1e30f;
  for (int i = 0; i < ksn; ++i) M = fmaxf(M, ml[(size_t)i * NN + row].x);
  float num = 0.f, L = 0.f;
  for (int i = 0; i < ksn; ++i) {
    float2 e = ml[(size_t)i * NN + row];
    float w = exp2f(e.x - M);
    L += w * e.y;
    num += w * b2f(opb[(size_t)i * NN * DD + (size_t)row * DD + c]);
  }
  hgb[(row << 8) | (c ^ ((row & 7) << 3))] = f2bf(num / L);
}

extern "C" void kernel_launch(void* const* d_in, const int* in_sizes, int n_in,
                              void* d_out, int out_size, void* d_ws, size_t ws_size,
                              hipStream_t stream) {
  (void)in_sizes; (void)n_in; (void)out_size;
  const float* h     = (const float*)d_in[0];
  const int*   ei    = (const int*)  d_in[1];
  const float* W_gcn = (const float*)d_in[2];
  const float* b_gcn = (const float*)d_in[3];
  const float* Wq    = (const float*)d_in[4];
  const float* bq    = (const float*)d_in[5];
  const float* Wk    = (const float*)d_in[6];
  const float* bk    = (const float*)d_in[7];
  const float* Wv    = (const float*)d_in[8];
  const float* bv    = (const float*)d_in[9];
  const float* Wo    = (const float*)d_in[10];
  const float* bo    = (const float*)d_in[11];
  const float* RF    = (const float*)d_in[12];
  const float* g1    = (const float*)d_in[13];
  const float* be1   = (const float*)d_in[14];
  const float* g2    = (const float*)d_in[15];
  const float* be2   = (const float*)d_in[16];
  const float* g3    = (const float*)d_in[17];
  const float* be3   = (const float*)d_in[18];
  const float* W1    = (const float*)d_in[19];
  const float* b1    = (const float*)d_in[20];
  const float* W2    = (const float*)d_in[21];
  const float* b2    = (const float*)d_in[22];
  float* out = (float*)d_out;

  const size_t M2 = (size_t)NN * DD;
  const int ksn = (ws_size >= (size_t)64 * 1024 * 1024) ? 8 : 4;
  const int kchunk = NN / ksn;

  char* base = (char*)d_ws;
  float*  h1   = (float*)base;  base += M2 * 4;
  ushort* hbX  = (ushort*)base; base += M2 * 2;   // hb, later hgb
  ushort* h1bX = (ushort*)base; base += M2 * 2;   // h1b, later h2b
  ushort* qb   = (ushort*)base; base += M2 * 2;
  ushort* kb   = (ushort*)base; base += M2 * 2;
  ushort* vbT  = (ushort*)base; base += M2 * 2;
  ushort* opb  = (ushort*)base;
  float*  R    = (float*)opb;   base += (size_t)ksn * M2 * 2;
  float*  mlf  = (float*)base;  base += (size_t)8 * NN * 2 * 4;
  ushort* WgcnT = (ushort*)base; base += DD * DD * 2;
  ushort* Wcat  = (ushort*)base; base += (size_t)768 * DD * 2;
  ushort* WoT   = (ushort*)base; base += DD * DD * 2;
  ushort* W1T   = (ushort*)base; base += FF * DD * 2;
  ushort* W2T   = (ushort*)base; base += DD * FF * 2;
  float*  bcat  = (float*)base;  base += 768 * 4;
  float*  dinv  = (float*)base;  base += NN * 4;
  int* degi    = (int*)base; base += NN * 4;
  int* cursor  = (int*)base; base += NN * 4;
  int* csr_off = (int*)base; base += (NN + 4) * 4;
  int* csr_src = (int*)base; base += EE * 4;

  // aliases
  ushort* xwb = (ushort*)R;        // bf16 xw, pre-flash (R region is opb during flash)
  float*  hgo = R;                 // post-merge
  float*  h2  = R + M2;            // post-merge
  ushort* tb  = qb;                // spans qb+kb, post-flash (8192x512 bf16)
  float*  f2  = h1;                // post-LN2 (h1 dead after LN2)
  ushort* hgb = hbX;
  ushort* h2b = h1bX;

  // CSR build
  init_kernel<<<NN / 256, 256, 0, stream>>>(degi, cursor);
  count_kernel<<<EE / 256, 256, 0, stream>>>(ei, degi);
  scan_kernel<<<1, 1024, 0, stream>>>(degi, csr_off, dinv);
  fill_kernel<<<EE / 256, 256, 0, stream>>>(ei, csr_off, cursor, csr_src);

  // precompute (fused)
  {
    const int total = NN * DD + 3 * DD * DD + 2 * DD * FF + DD;
    prep1_kernel<<<(total + 255) / 256, 256, 0, stream>>>(
        h, W_gcn, Wv, Wo, W1, W2, bv, hbX, WgcnT, Wcat, WoT, W1T, W2T, bcat);
  }
  prep2_kernel<<<514, 256, 0, stream>>>(Wq, Wk, bq, bk, RF, Wcat, bcat);

  // xw = h @ W_gcn (bf16 plain out -> L2-resident gather source)
  gemm_bf16_kernel<4, false><<<dim3(DD / 64, NN / 64), 256, 0, stream>>>(
      hbX, WgcnT, nullptr, xwb, nullptr, nullptr, NN, DD, DD);
  // local GCN + LN1
  gcn_gather_ln_kernel<<<NN, 256, 0, stream>>>(xwb, h, dinv, csr_off, csr_src, b_gcn, g1, be1, h1, h1bX);
  // fused q/k/v projections (single GEMM, routed epilogue)
  gemm_bf16_kernel<3, false><<<dim3(768 / 64, NN / 64), 256, 0, stream>>>(
      h1bX, Wcat, bcat, qb, kb, vbT, NN, 768, DD);
  // attention
  flash_mfma_kernel<<<(NN / 128) * ksn, 256, 0, stream>>>(qb, kb, vbT, opb, (float2*)mlf, ksn, kchunk);
  flash_merge_kernel<<<NN, 256, 0, stream>>>(opb, (const float2*)mlf, hgb, ksn);
  // output projection + LN2
  gemm_bf16_kernel<0, false><<<dim3(DD / 64, NN / 64), 256, 0, stream>>>(
      hgb, WoT, bo, hgo, nullptr, nullptr, NN, DD, DD);
  ln_res_kernel<<<NN, 256, 0, stream>>>(h1, hgo, g2, be2, h2, h2b);
  // FFN + LN3
  gemm_bf16_kernel<1, true ><<<dim3(FF / 64, NN / 64), 256, 0, stream>>>(
      h2b, W1T, b1, tb, nullptr, nullptr, NN, FF, DD);
  gemm_bf16_kernel<0, false><<<dim3(DD / 64, NN / 64), 256, 0, stream>>>(
      tb, W2T, b2, f2, nullptr, nullptr, NN, DD, FF);
  ln_res_kernel<<<NN, 256, 0, stream>>>(h2, f2, g3, be3, out, nullptr);
}